// Round 5
// baseline (5007.365 us; speedup 1.0000x reference)
//
#include <hip/hip_runtime.h>

constexpr int B_ = 128, S_ = 25, NF_ = 196, ENC_ = 512, ATT_ = 512;
constexpr int H_ = 512, E_ = 256, V_ = 10000, G4_ = 2048;
constexpr int VPAD_ = 10112;  // 79*128

typedef __attribute__((ext_vector_type(8))) __bf16 bf16x8;
typedef __attribute__((ext_vector_type(4))) __bf16 bf16x4;
typedef __attribute__((ext_vector_type(4))) float f32x4;

__device__ __forceinline__ float bflo(unsigned u) {
    return __builtin_bit_cast(float, u << 16);
}
__device__ __forceinline__ float bfhi(unsigned u) {
    return __builtin_bit_cast(float, u & 0xffff0000u);
}
__device__ __forceinline__ float fast_tanhf(float x) {
    x = fminf(fmaxf(x, -15.f), 15.f);
    return 1.f - 2.f * __fdividef(1.f, __expf(2.f * x) + 1.f);
}
__device__ __forceinline__ float fast_sigf(float x) {
    x = fminf(fmaxf(x, -30.f), 30.f);
    return __fdividef(1.f, 1.f + __expf(-x));
}

// ---------------- sharded grid barrier: R3-proven acquire semantics, 8 shards ----------------
__device__ __forceinline__ void gridbar(int* bar, int idx) {
    __syncthreads();              // drains vmcnt: all block stores in L2
    if (threadIdx.x == 0) {
        __threadfence();          // agent release (L2 writeback)
        atomicAdd(&bar[idx * 128 + (blockIdx.x & 7) * 16], 1);
        int sum;
        do {
            sum = 0;
#pragma unroll
            for (int i = 0; i < 8; ++i)
                sum += __hip_atomic_load(&bar[idx * 128 + i * 16],
                                         __ATOMIC_ACQUIRE, __HIP_MEMORY_SCOPE_AGENT);
            if (sum < 256) __builtin_amdgcn_s_sleep(2);
        } while (sum < 256);
    }
    __syncthreads();
}

// ---------------- setup kernels (all R3-proven) ----------------
__global__ __launch_bounds__(256) void k_zero(int* bar) {
    int i = blockIdx.x * 256 + threadIdx.x;
    if (i < 9600) bar[i] = 0;
}

__global__ __launch_bounds__(256) void k_cvt(const float* __restrict__ s,
                                             __bf16* __restrict__ d, int n4) {
    int i = blockIdx.x * 256 + threadIdx.x;
    if (i >= n4) return;
    float4 v = *(const float4*)&s[(size_t)i * 4];
    bf16x4 o;
    o[0] = (__bf16)v.x; o[1] = (__bf16)v.y; o[2] = (__bf16)v.z; o[3] = (__bf16)v.w;
    *(bf16x4*)&d[(size_t)i * 4] = o;
}

__global__ __launch_bounds__(256) void k_cvt_fcw(const float* __restrict__ s,
                                                 __bf16* __restrict__ d) {
    int i = blockIdx.x * 256 + threadIdx.x;
    if (i >= VPAD_ * 512 / 4) return;
    int e = i * 4;
    int row = e >> 9;
    bf16x4 o;
    if (row < V_) {
        float4 v = *(const float4*)&s[(size_t)row * 512 + (e & 511)];
        o[0] = (__bf16)v.x; o[1] = (__bf16)v.y; o[2] = (__bf16)v.z; o[3] = (__bf16)v.w;
    } else {
        o[0] = o[1] = o[2] = o[3] = (__bf16)0.f;
    }
    *(bf16x4*)&d[(size_t)e] = o;
}

// Ww[j][k] f32 -> W2[k][jp] u32 = pack(bf16 Ww[2jp][k], bf16 Ww[2jp+1][k])
__global__ __launch_bounds__(256) void k_pack_ww(const float* __restrict__ Ww,
                                                 unsigned* __restrict__ W2) {
    __shared__ float Ts[32][65];
    int t = threadIdx.x;
    int k0 = blockIdx.x * 32, j0 = blockIdx.y * 64;
    int c = t & 31, rr = t >> 5;
#pragma unroll
    for (int i = 0; i < 8; ++i) {
        int j = j0 + rr + i * 8;
        Ts[c][rr + i * 8] = Ww[(size_t)j * 512 + k0 + c];
    }
    __syncthreads();
#pragma unroll
    for (int i = 0; i < 4; ++i) {
        int kr = (t >> 5) + i * 8;
        int jc = t & 31;
        __bf16 b0 = (__bf16)Ts[kr][2 * jc], b1 = (__bf16)Ts[kr][2 * jc + 1];
        unsigned u = (unsigned)__builtin_bit_cast(unsigned short, b0)
                   | ((unsigned)__builtin_bit_cast(unsigned short, b1) << 16);
        W2[(size_t)(k0 + kr) * 256 + (j0 >> 1) + jc] = u;
    }
}

__global__ __launch_bounds__(256) void k_cvt_wih(const float* __restrict__ W_ih,
                                                 __bf16* __restrict__ o) {
    int n = blockIdx.x, k = threadIdx.x;
    o[(size_t)n * 256 + k] = (__bf16)W_ih[(size_t)n * 768 + k];
}

__global__ __launch_bounds__(256) void k_embed(const int* __restrict__ dec,
                                               const float* __restrict__ emb,
                                               const float* __restrict__ pose,
                                               __bf16* __restrict__ out) {
    int bx = blockIdx.x;
    int s = bx >> 7, b = bx & 127;
    int e = threadIdx.x;
    int tok = dec[b * S_ + s];
    out[(size_t)bx * E_ + e] = (__bf16)(emb[tok * E_ + e] + pose[s * E_ + e]);
}

__global__ __launch_bounds__(256) void k_init(const float* __restrict__ enc,
                                              const float* __restrict__ ihw, const float* __restrict__ ihb,
                                              const float* __restrict__ icw, const float* __restrict__ icb,
                                              float* __restrict__ Hall, float* __restrict__ cbuf) {
    __shared__ __align__(16) float mean[ENC_];
    int b = blockIdx.x, t = threadIdx.x;
    for (int d = t; d < ENC_; d += 256) {
        float sum = 0.f;
        for (int n = 0; n < NF_; ++n) sum += enc[(b * NF_ + n) * ENC_ + d];
        mean[d] = sum * (1.f / NF_);
    }
    __syncthreads();
    for (int j = t; j < H_; j += 256) {
        float ah = 0.f, ac = 0.f;
        const float4* wh = (const float4*)&ihw[j * ENC_];
        const float4* wc = (const float4*)&icw[j * ENC_];
        for (int d4 = 0; d4 < ENC_ / 4; ++d4) {
            float4 m4 = *(const float4*)&mean[d4 * 4];
            float4 h4 = wh[d4], c4 = wc[d4];
            ah += m4.x * h4.x + m4.y * h4.y + m4.z * h4.z + m4.w * h4.w;
            ac += m4.x * c4.x + m4.y * c4.y + m4.z * c4.z + m4.w * c4.w;
        }
        Hall[b * H_ + j] = ah + ihb[j];
        cbuf[b * H_ + j] = ac + icb[j];
    }
}

// ---------------- bf16 MFMA GEMM (R2/R3-proven) ----------------
template<int MODE>
__global__ __launch_bounds__(256) void k_mfma_gemm(
    const __bf16* __restrict__ A, const __bf16* __restrict__ Bm,
    const float* __restrict__ bias1, const float* __restrict__ bias2,
    void* __restrict__ Cout, int K, int Nreal, int ldc) {
    __shared__ __align__(16) __bf16 As[128 * 64];
    __shared__ __align__(16) __bf16 Bs[128 * 64];
    int tid = threadIdx.x;
    int lane = tid & 63, w = tid >> 6;
    int m0 = blockIdx.x * 128, n0 = blockIdx.y * 128;
    int wm = (w & 1) * 64, wn = (w >> 1) * 64;
    f32x4 acc[4][4] = {};
    int srow = tid >> 3;
    int ke = (tid & 7) * 8;
    int kgw = tid & 7;

    for (int k0 = 0; k0 < K; k0 += 64) {
#pragma unroll
        for (int it = 0; it < 4; ++it) {
            int row = it * 32 + srow;
            bf16x8 av = *(const bf16x8*)(A + (size_t)(m0 + row) * K + k0 + ke);
            bf16x8 bv = *(const bf16x8*)(Bm + (size_t)(n0 + row) * K + k0 + ke);
            int kg = kgw ^ (row & 7);
            *(bf16x8*)&As[row * 64 + kg * 8] = av;
            *(bf16x8*)&Bs[row * 64 + kg * 8] = bv;
        }
        __syncthreads();
        bf16x8 af[4][2], bfr[4][2];
#pragma unroll
        for (int f = 0; f < 4; ++f) {
#pragma unroll
            for (int ks = 0; ks < 2; ++ks) {
                int ra = wm + f * 16 + (lane & 15);
                int rb = wn + f * 16 + (lane & 15);
                int kgl = ks * 4 + (lane >> 4);
                af[f][ks]  = *(const bf16x8*)&As[ra * 64 + (kgl ^ (ra & 7)) * 8];
                bfr[f][ks] = *(const bf16x8*)&Bs[rb * 64 + (kgl ^ (rb & 7)) * 8];
            }
        }
#pragma unroll
        for (int fm = 0; fm < 4; ++fm)
#pragma unroll
            for (int fn = 0; fn < 4; ++fn)
#pragma unroll
                for (int ks = 0; ks < 2; ++ks)
                    acc[fm][fn] = __builtin_amdgcn_mfma_f32_16x16x32_bf16(
                        af[fm][ks], bfr[fn][ks], acc[fm][fn], 0, 0, 0);
        __syncthreads();
    }
    int cm = (lane >> 4) * 4, cn = lane & 15;
#pragma unroll
    for (int fm = 0; fm < 4; ++fm) {
#pragma unroll
        for (int fn = 0; fn < 4; ++fn) {
#pragma unroll
            for (int r = 0; r < 4; ++r) {
                int gm = m0 + wm + fm * 16 + cm + r;
                int gn = n0 + wn + fn * 16 + cn;
                float v = acc[fm][fn][r];
                if (MODE == 0) {
                    if (gn < Nreal) {
                        int orow = (gm & 127) * S_ + (gm >> 7);
                        ((float*)Cout)[(size_t)orow * ldc + gn] = v + bias1[gn];
                    }
                } else if (MODE == 1) {
                    ((__bf16*)Cout)[(size_t)gm * ldc + gn] = (__bf16)(v + bias1[gn]);
                } else {
                    ((float*)Cout)[(size_t)gm * ldc + gn] = v + bias1[gn] + bias2[gn];
                }
            }
        }
    }
}

// ---------------- persistent recurrence: 256 blocks x 1024 thr, lockstep A/B/C, 75 barriers ----------------
// A: (b2=bid>>1, nh=bid&1) w_ah (redundant x2) + scores for nh-half -> sc_g
// B: softmax (tree) + ctx partials for nh-half -> ctxp[nh]
// C: (half=bid&1, jh0=(bid>>1)*4) gates GEMM K=1024 + LSTM pointwise -> Hall[s+1]
__global__ __launch_bounds__(1024) void k_steps(
    const __bf16* __restrict__ u_hs,      // [25088][512]
    const unsigned* __restrict__ enc2,    // enc bf16 pairs [25088][256]
    const unsigned* __restrict__ W2,      // [512][256] packed Ww^T
    const float* __restrict__ Wb,
    const float* __restrict__ Aw,
    const float* __restrict__ W_ih,       // [2048][768]
    const float* __restrict__ W_hh,       // [2048][512]
    const float* __restrict__ gatespre,   // [3200][2048]
    float* __restrict__ Hall,             // [26][128][512]
    __bf16* __restrict__ Hall_bf,
    float* __restrict__ cbuf,
    float* __restrict__ sc_g,             // [128][196]
    float* __restrict__ ctxp,             // [2][128][512]
    float* __restrict__ alphas,
    int* __restrict__ bar) {
    __shared__ __align__(16) float sm[10432];
    // attn: [0,512) h | [512,1024) wah | [1024,3072) partials | [3072,3328) red | [3328,3524) al
    constexpr int WAH = 512, PART = 1024, RED = 3072, AL = 3328;
    // gates: [0,8256) Ws 16x516 | [8256,9344) Gs 64x17
    constexpr int GS = 8256;

    int bid = blockIdx.x, t = threadIdx.x;
    int w = t >> 6, ln = t & 63;
    int b2 = bid >> 1, nh = bid & 1;                  // phases A,B
    int half = bid & 1, jh0 = (bid >> 1) * 4;         // phase C
    int cc = t & 15, bb = t >> 4;                     // C compute: col cc, batch bb (0..63)
    int wrow = (cc >> 2) * 512 + jh0 + (cc & 3);
    int rr = t >> 6, k8 = (t & 63) * 8;               // C staging
    int srow = (rr >> 2) * 512 + jh0 + (rr & 3);
    int gb = half * 64 + bb;

    float av[8];
#pragma unroll
    for (int i = 0; i < 8; ++i) av[i] = Aw[ln * 8 + i];

    for (int s = 0; s < S_; ++s) {
        // ================= Phase A =================
        if (t < 512) sm[t] = Hall[(size_t)s * 65536 + b2 * 512 + t];
        __syncthreads();
        if (t < 256) {            // w_ah: R3-proven full-K per thread (j-pair t)
            float a0 = Wb[2 * t], a1 = Wb[2 * t + 1];
            const float4* h4 = (const float4*)sm;
#pragma unroll 2
            for (int k4 = 0; k4 < 128; ++k4) {
                float4 hk = h4[k4];
                unsigned w0 = W2[(k4 * 4 + 0) * 256 + t];
                unsigned w1 = W2[(k4 * 4 + 1) * 256 + t];
                unsigned w2 = W2[(k4 * 4 + 2) * 256 + t];
                unsigned w3 = W2[(k4 * 4 + 3) * 256 + t];
                a0 += hk.x * bflo(w0); a1 += hk.x * bfhi(w0);
                a0 += hk.y * bflo(w1); a1 += hk.y * bfhi(w1);
                a0 += hk.z * bflo(w2); a1 += hk.z * bfhi(w2);
                a0 += hk.w * bflo(w3); a1 += hk.w * bfhi(w3);
            }
            sm[WAH + 2 * t] = a0; sm[WAH + 2 * t + 1] = a1;
        }
        __syncthreads();
        {                          // scores: 98 rows over 16 waves
            float wv[8];
#pragma unroll
            for (int i = 0; i < 8; ++i) wv[i] = sm[WAH + ln * 8 + i];
            for (int n0 = w; n0 < 98; n0 += 16) {
                int n = nh * 98 + n0;
                bf16x8 u8 = *(const bf16x8*)(u_hs + ((size_t)(b2 * 196 + n)) * 512 + ln * 8);
                float acc = 0.f;
#pragma unroll
                for (int i = 0; i < 8; ++i)
                    acc += fast_tanhf((float)u8[i] + wv[i]) * av[i];
#pragma unroll
                for (int off = 32; off; off >>= 1) acc += __shfl_xor(acc, off);
                if (ln == 0) sc_g[b2 * 196 + n] = acc;   // Ab omitted (cancels)
            }
        }
        gridbar(bar, s * 3 + 0);
        // ================= Phase B =================
        {
            if (t < 256) sm[RED + t] = (t < 196) ? sc_g[b2 * 196 + t] : -1e30f;
            __syncthreads();
#pragma unroll
            for (int off = 128; off; off >>= 1) {
                if (t < off) sm[RED + t] = fmaxf(sm[RED + t], sm[RED + t + off]);
                __syncthreads();
            }
            float mx = sm[RED];
            __syncthreads();
            float e = (t < 196) ? __expf(sc_g[b2 * 196 + t] - mx) : 0.f;
            if (t < 256) sm[RED + t] = e;
            __syncthreads();
#pragma unroll
            for (int off = 128; off; off >>= 1) {
                if (t < off) sm[RED + t] += sm[RED + t + off];
                __syncthreads();
            }
            float inv = __fdividef(1.f, sm[RED]);
            __syncthreads();
            if (t < 196) {
                float a = e * inv;
                sm[AL + t] = a;
                alphas[((size_t)b2 * 25 + s) * 196 + t] = a;  // both nh write same value
            }
            __syncthreads();
            // ctx partials: 4-way row interleave over this block's 98 rows
            int p = t & 255, q = t >> 8;
            float c0 = 0.f, c1 = 0.f;
            for (int i = q; i < 98; i += 4) {
                unsigned u = enc2[((size_t)(b2 * 196 + nh * 98 + i)) * 256 + p];
                float a = sm[AL + nh * 98 + i];
                c0 += a * bflo(u); c1 += a * bfhi(u);
            }
            sm[PART + q * 512 + 2 * p] = c0;
            sm[PART + q * 512 + 2 * p + 1] = c1;
            __syncthreads();
            if (t < 512)
                ctxp[((size_t)(nh * 128 + b2)) * 512 + t] =
                    sm[PART + t] + sm[PART + 512 + t] + sm[PART + 1024 + t] + sm[PART + 1536 + t];
        }
        gridbar(bar, s * 3 + 1);
        // ================= Phase C =================
        {
            // round 1: h @ W_hh
            {
                const float* wp = W_hh + (size_t)srow * 512 + k8;
                *(float4*)&sm[rr * 516 + k8] = *(const float4*)wp;
                *(float4*)&sm[rr * 516 + k8 + 4] = *(const float4*)(wp + 4);
            }
            __syncthreads();
            float a0 = 0.f;
            {
                const float* xa = Hall + (size_t)s * 65536 + gb * 512;
#pragma unroll 4
                for (int k = 0; k < 512; k += 4) {
                    float4 w4 = *(const float4*)&sm[cc * 516 + k];
                    float4 x4 = *(const float4*)&xa[k];
                    a0 += w4.x * x4.x + w4.y * x4.y + w4.z * x4.z + w4.w * x4.w;
                }
            }
            __syncthreads();     // done reading Ws before overwrite
            // round 2: ctx @ W_ih[:,256:768]
            {
                const float* wp = W_ih + (size_t)srow * 768 + 256 + k8;
                *(float4*)&sm[rr * 516 + k8] = *(const float4*)wp;
                *(float4*)&sm[rr * 516 + k8 + 4] = *(const float4*)(wp + 4);
            }
            __syncthreads();
            {
                const float* xa = ctxp + (size_t)gb * 512;            // ctxp[0]
                const float* xb = ctxp + (size_t)(128 + gb) * 512;    // ctxp[1]
#pragma unroll 4
                for (int k = 0; k < 512; k += 4) {
                    float4 w4 = *(const float4*)&sm[cc * 516 + k];
                    float4 x4 = *(const float4*)&xa[k];
                    float4 y4 = *(const float4*)&xb[k];
                    a0 += w4.x * (x4.x + y4.x) + w4.y * (x4.y + y4.y)
                        + w4.z * (x4.z + y4.z) + w4.w * (x4.w + y4.w);
                }
            }
            sm[GS + bb * 17 + cc] = a0 + gatespre[((size_t)s * 128 + gb) * 2048 + wrow];
            __syncthreads();
            if (t < 256) {
                int bp = t >> 2, u = t & 3;
                float qi = sm[GS + bp * 17 + u];
                float qf = sm[GS + bp * 17 + 4 + u];
                float qg = sm[GS + bp * 17 + 8 + u];
                float qo = sm[GS + bp * 17 + 12 + u];
                float ig = fast_sigf(qi), fg = fast_sigf(qf);
                float gg = fast_tanhf(qg), og = fast_sigf(qo);
                int gbb = half * 64 + bp;
                int ci = gbb * 512 + jh0 + u;
                float cn = fg * cbuf[ci] + ig * gg;
                float hn = og * fast_tanhf(cn);
                cbuf[ci] = cn;
                Hall[(size_t)(s + 1) * 65536 + ci] = hn;
                Hall_bf[(size_t)(s + 1) * 65536 + ci] = (__bf16)hn;
            }
        }
        gridbar(bar, s * 3 + 2);
    }
}

extern "C" void kernel_launch(void* const* d_in, const int* in_sizes, int n_in,
                              void* d_out, int out_size, void* d_ws, size_t ws_size,
                              hipStream_t stream) {
    const int*   dec  = (const int*)d_in[0];
    const float* enc  = (const float*)d_in[1];
    const float* emb  = (const float*)d_in[2];
    const float* pose = (const float*)d_in[3];
    const float* Uw   = (const float*)d_in[4];
    const float* Ub   = (const float*)d_in[5];
    const float* Ww   = (const float*)d_in[6];
    const float* Wb   = (const float*)d_in[7];
    const float* Aw   = (const float*)d_in[8];
    // d_in[9] = Ab: cancels in softmax
    const float* ihw  = (const float*)d_in[10];
    const float* ihb  = (const float*)d_in[11];
    const float* icw  = (const float*)d_in[12];
    const float* icb  = (const float*)d_in[13];
    const float* W_ih = (const float*)d_in[14];
    const float* W_hh = (const float*)d_in[15];
    const float* b_ih = (const float*)d_in[16];
    const float* b_hh = (const float*)d_in[17];
    const float* fcw  = (const float*)d_in[18];
    const float* fcb  = (const float*)d_in[19];
    float* out = (float*)d_out;
    char*  wsb = (char*)d_ws;

    // ---- workspace layout (bytes), ~92.5 MB; fcw_bf aliases enc_bf (dead after k_steps) ----
    size_t o = 0;
    __bf16*   enc_bf   = (__bf16*)(wsb + o);
    __bf16*   fcw_bf   = (__bf16*)(wsb + o); o += (size_t)25088 * 512 * 2;
    __bf16*   u_hs_bf  = (__bf16*)(wsb + o); o += (size_t)25088 * 512 * 2;
    float*    gatespre = (float*)(wsb + o);  o += (size_t)3200 * 2048 * 4;
    float*    Hall     = (float*)(wsb + o);  o += (size_t)26 * 65536 * 4;
    __bf16*   Hall_bf  = (__bf16*)(wsb + o); o += (size_t)26 * 65536 * 2;
    float*    cbuf     = (float*)(wsb + o);  o += (size_t)65536 * 4;
    float*    sc_g     = (float*)(wsb + o);  o += (size_t)128 * 196 * 4;
    float*    ctxp     = (float*)(wsb + o);  o += (size_t)2 * 65536 * 4;
    __bf16*   Uw_bf    = (__bf16*)(wsb + o); o += (size_t)262144 * 2;
    unsigned* W2       = (unsigned*)(wsb + o); o += (size_t)512 * 256 * 4;
    __bf16*   WihE_bf  = (__bf16*)(wsb + o); o += (size_t)2048 * 256 * 2;
    __bf16*   embeds_bf= (__bf16*)(wsb + o); o += (size_t)3200 * 256 * 2;
    int*      bar      = (int*)(wsb + o);    o += 9600 * 4;

    // ---- setup ----
    k_zero<<<38, 256, 0, stream>>>(bar);
    k_cvt<<<12544, 256, 0, stream>>>(enc, enc_bf, 3211264);
    k_cvt<<<256, 256, 0, stream>>>(Uw, Uw_bf, 65536);
    k_pack_ww<<<dim3(16, 8), 256, 0, stream>>>(Ww, W2);
    k_cvt_wih<<<2048, 256, 0, stream>>>(W_ih, WihE_bf);
    k_embed<<<S_ * B_, 256, 0, stream>>>(dec, emb, pose, embeds_bf);
    k_init<<<B_, 256, 0, stream>>>(enc, ihw, ihb, icw, icb, Hall, cbuf);

    // u_hs = enc @ Uw^T + Ub -> bf16 [25088,512]
    k_mfma_gemm<1><<<dim3(196, 4), 256, 0, stream>>>(enc_bf, Uw_bf, Ub, nullptr,
                                                     u_hs_bf, 512, 512, 512);
    // gates_pre = embeds @ W_ih[:, :256]^T + b_ih + b_hh -> f32 [3200,2048]
    k_mfma_gemm<2><<<dim3(25, 16), 256, 0, stream>>>(embeds_bf, WihE_bf, b_ih, b_hh,
                                                     gatespre, 256, 2048, 2048);

    // ---- the 25-step recurrence: one persistent kernel ----
    k_steps<<<256, 1024, 0, stream>>>(u_hs_bf, (const unsigned*)enc_bf, W2, Wb, Aw,
                                      W_ih, W_hh, gatespre, Hall, Hall_bf, cbuf,
                                      sc_g, ctxp, out + 32000000, bar);

    // fcw -> bf16 (aliases enc_bf, dead after k_steps)
    k_cvt_fcw<<<5056, 256, 0, stream>>>(fcw, fcw_bf);
    // outs = Hall_bf[1..25] @ fcn_w^T + fcn_b -> f32 [B,S,V]
    k_mfma_gemm<0><<<dim3(25, 79), 256, 0, stream>>>(Hall_bf + 65536, fcw_bf, fcb, nullptr,
                                                     out, 512, V_, V_);
}

// Round 6
// 2244.104 us; speedup vs baseline: 2.2313x; 2.2313x over previous
//
#include <hip/hip_runtime.h>

constexpr int B_ = 128, S_ = 25, NF_ = 196, ENC_ = 512, ATT_ = 512;
constexpr int H_ = 512, E_ = 256, V_ = 10000, G4_ = 2048;
constexpr int VPAD_ = 10112;  // 79*128

typedef __attribute__((ext_vector_type(8))) __bf16 bf16x8;
typedef __attribute__((ext_vector_type(4))) __bf16 bf16x4;
typedef __attribute__((ext_vector_type(4))) float f32x4;

__device__ __forceinline__ float bflo(unsigned u) {
    return __builtin_bit_cast(float, u << 16);
}
__device__ __forceinline__ float bfhi(unsigned u) {
    return __builtin_bit_cast(float, u & 0xffff0000u);
}
__device__ __forceinline__ float fast_tanhf(float x) {
    x = fminf(fmaxf(x, -15.f), 15.f);
    return 1.f - 2.f * __fdividef(1.f, __expf(2.f * x) + 1.f);
}
__device__ __forceinline__ float fast_sigf(float x) {
    x = fminf(fmaxf(x, -30.f), 30.f);
    return __fdividef(1.f, 1.f + __expf(-x));
}

// gate-interleaved permutation: col n -> weight row pi(n)
__device__ __forceinline__ int gperm(int n) {
    int j = (n & 15) + ((n >> 6) << 4);
    int g = (n >> 4) & 3;
    return g * 512 + j;
}

// ---------------- setup kernels ----------------
__global__ __launch_bounds__(256) void k_cvt(const float* __restrict__ s,
                                             __bf16* __restrict__ d, int n4) {
    int i = blockIdx.x * 256 + threadIdx.x;
    if (i >= n4) return;
    float4 v = *(const float4*)&s[(size_t)i * 4];
    bf16x4 o;
    o[0] = (__bf16)v.x; o[1] = (__bf16)v.y; o[2] = (__bf16)v.z; o[3] = (__bf16)v.w;
    *(bf16x4*)&d[(size_t)i * 4] = o;
}

__global__ __launch_bounds__(256) void k_cvt_fcw(const float* __restrict__ s,
                                                 __bf16* __restrict__ d) {
    int i = blockIdx.x * 256 + threadIdx.x;
    if (i >= VPAD_ * 512 / 4) return;
    int e = i * 4;
    int row = e >> 9;
    bf16x4 o;
    if (row < V_) {
        float4 v = *(const float4*)&s[(size_t)row * 512 + (e & 511)];
        o[0] = (__bf16)v.x; o[1] = (__bf16)v.y; o[2] = (__bf16)v.z; o[3] = (__bf16)v.w;
    } else {
        o[0] = o[1] = o[2] = o[3] = (__bf16)0.f;
    }
    *(bf16x4*)&d[(size_t)e] = o;
}

// Ww[j][k] f32 -> W2[k][jp] u32 = pack(bf16 Ww[2jp][k], bf16 Ww[2jp+1][k])  (R3/R5-proven)
__global__ __launch_bounds__(256) void k_pack_ww(const float* __restrict__ Ww,
                                                 unsigned* __restrict__ W2) {
    __shared__ float Ts[32][65];
    int t = threadIdx.x;
    int k0 = blockIdx.x * 32, j0 = blockIdx.y * 64;
    int c = t & 31, rr = t >> 5;
#pragma unroll
    for (int i = 0; i < 8; ++i) {
        int j = j0 + rr + i * 8;
        Ts[c][rr + i * 8] = Ww[(size_t)j * 512 + k0 + c];
    }
    __syncthreads();
#pragma unroll
    for (int i = 0; i < 4; ++i) {
        int kr = (t >> 5) + i * 8;
        int jc = t & 31;
        __bf16 b0 = (__bf16)Ts[kr][2 * jc], b1 = (__bf16)Ts[kr][2 * jc + 1];
        unsigned u = (unsigned)__builtin_bit_cast(unsigned short, b0)
                   | ((unsigned)__builtin_bit_cast(unsigned short, b1) << 16);
        W2[(size_t)(k0 + kr) * 256 + (j0 >> 1) + jc] = u;
    }
}

// W_ih[:, :256] permuted rows -> bf16 [2048][256] (gate-interleaved)
__global__ __launch_bounds__(256) void k_cvt_wih_r(const float* __restrict__ W_ih,
                                                   __bf16* __restrict__ o) {
    int n = blockIdx.x, k = threadIdx.x;
    int row = gperm(n);
    o[(size_t)n * 256 + k] = (__bf16)W_ih[(size_t)row * 768 + k];
}

// Wcat[n][k]: k<512 -> W_ih[pi(n)][256+k], else W_hh[pi(n)][k-512]   (bf16)
__global__ __launch_bounds__(256) void k_pack_wcat(const float* __restrict__ W_ih,
                                                   const float* __restrict__ W_hh,
                                                   __bf16* __restrict__ Wcat) {
    int n = blockIdx.x, t = threadIdx.x;
    int row = gperm(n);
#pragma unroll
    for (int i = 0; i < 4; ++i) {
        int k = t + i * 256;
        float v = (k < 512) ? W_ih[(size_t)row * 768 + 256 + k]
                            : W_hh[(size_t)row * 512 + (k - 512)];
        Wcat[(size_t)n * 1024 + k] = (__bf16)v;
    }
}

__global__ __launch_bounds__(256) void k_pack_biasr(const float* __restrict__ b_ih,
                                                    const float* __restrict__ b_hh,
                                                    float* __restrict__ bsum_r) {
    int n = blockIdx.x * 256 + threadIdx.x;
    int row = gperm(n);
    bsum_r[n] = b_ih[row] + b_hh[row];
}

__global__ __launch_bounds__(256) void k_embed(const int* __restrict__ dec,
                                               const float* __restrict__ emb,
                                               const float* __restrict__ pose,
                                               __bf16* __restrict__ out) {
    int bx = blockIdx.x;
    int s = bx >> 7, b = bx & 127;
    int e = threadIdx.x;
    int tok = dec[b * S_ + s];
    out[(size_t)bx * E_ + e] = (__bf16)(emb[tok * E_ + e] + pose[s * E_ + e]);
}

// mean_enc -> h0 (bf16 into Abuf0 h-part), c0 (f32 cbuf)
__global__ __launch_bounds__(256) void k_init(const float* __restrict__ enc,
                                              const float* __restrict__ ihw, const float* __restrict__ ihb,
                                              const float* __restrict__ icw, const float* __restrict__ icb,
                                              __bf16* __restrict__ Abuf0, float* __restrict__ cbuf) {
    __shared__ __align__(16) float mean[ENC_];
    int b = blockIdx.x, t = threadIdx.x;
    for (int d = t; d < ENC_; d += 256) {
        float sum = 0.f;
        for (int n = 0; n < NF_; ++n) sum += enc[(b * NF_ + n) * ENC_ + d];
        mean[d] = sum * (1.f / NF_);
    }
    __syncthreads();
    for (int j = t; j < H_; j += 256) {
        float ah = 0.f, ac = 0.f;
        const float4* wh = (const float4*)&ihw[j * ENC_];
        const float4* wc = (const float4*)&icw[j * ENC_];
        for (int d4 = 0; d4 < ENC_ / 4; ++d4) {
            float4 m4 = *(const float4*)&mean[d4 * 4];
            float4 h4 = wh[d4], c4 = wc[d4];
            ah += m4.x * h4.x + m4.y * h4.y + m4.z * h4.z + m4.w * h4.w;
            ac += m4.x * c4.x + m4.y * c4.y + m4.z * c4.z + m4.w * c4.w;
        }
        Abuf0[(size_t)b * 1024 + 512 + j] = (__bf16)(ah + ihb[j]);
        cbuf[b * H_ + j] = ac + icb[j];
    }
}

// ---------------- bf16 MFMA GEMM (proven core, + lda param) ----------------
// MODE 0: f32 out, remap row (s*128+b -> b*25+s), guard n<Nreal, +bias (fcn)
// MODE 1: bf16 out, +bias (u_hs, gatespre)
template<int MODE>
__global__ __launch_bounds__(256) void k_mfma_gemm(
    const __bf16* __restrict__ A, int lda, const __bf16* __restrict__ Bm,
    const float* __restrict__ bias1, void* __restrict__ Cout,
    int K, int Nreal, int ldc) {
    __shared__ __align__(16) __bf16 As[128 * 64];
    __shared__ __align__(16) __bf16 Bs[128 * 64];
    int tid = threadIdx.x;
    int lane = tid & 63, w = tid >> 6;
    int m0 = blockIdx.x * 128, n0 = blockIdx.y * 128;
    int wm = (w & 1) * 64, wn = (w >> 1) * 64;
    f32x4 acc[4][4] = {};
    int srow = tid >> 3;
    int ke = (tid & 7) * 8;
    int kgw = tid & 7;

    for (int k0 = 0; k0 < K; k0 += 64) {
#pragma unroll
        for (int it = 0; it < 4; ++it) {
            int row = it * 32 + srow;
            bf16x8 av = *(const bf16x8*)(A + (size_t)(m0 + row) * lda + k0 + ke);
            bf16x8 bv = *(const bf16x8*)(Bm + (size_t)(n0 + row) * K + k0 + ke);
            int kg = kgw ^ (row & 7);
            *(bf16x8*)&As[row * 64 + kg * 8] = av;
            *(bf16x8*)&Bs[row * 64 + kg * 8] = bv;
        }
        __syncthreads();
        bf16x8 af[4][2], bfr[4][2];
#pragma unroll
        for (int f = 0; f < 4; ++f) {
#pragma unroll
            for (int ks = 0; ks < 2; ++ks) {
                int ra = wm + f * 16 + (lane & 15);
                int rb = wn + f * 16 + (lane & 15);
                int kgl = ks * 4 + (lane >> 4);
                af[f][ks]  = *(const bf16x8*)&As[ra * 64 + (kgl ^ (ra & 7)) * 8];
                bfr[f][ks] = *(const bf16x8*)&Bs[rb * 64 + (kgl ^ (rb & 7)) * 8];
            }
        }
#pragma unroll
        for (int fm = 0; fm < 4; ++fm)
#pragma unroll
            for (int fn = 0; fn < 4; ++fn)
#pragma unroll
                for (int ks = 0; ks < 2; ++ks)
                    acc[fm][fn] = __builtin_amdgcn_mfma_f32_16x16x32_bf16(
                        af[fm][ks], bfr[fn][ks], acc[fm][fn], 0, 0, 0);
        __syncthreads();
    }
    int cm = (lane >> 4) * 4, cn = lane & 15;
#pragma unroll
    for (int fm = 0; fm < 4; ++fm) {
#pragma unroll
        for (int fn = 0; fn < 4; ++fn) {
#pragma unroll
            for (int r = 0; r < 4; ++r) {
                int gm = m0 + wm + fm * 16 + cm + r;
                int gn = n0 + wn + fn * 16 + cn;
                float v = acc[fm][fn][r];
                if (MODE == 0) {
                    if (gn < Nreal) {
                        int orow = (gm & 127) * S_ + (gm >> 7);
                        ((float*)Cout)[(size_t)orow * ldc + gn] = v + bias1[gn];
                    }
                } else {
                    ((__bf16*)Cout)[(size_t)gm * ldc + gn] = (__bf16)(v + bias1[gn]);
                }
            }
        }
    }
}

// ---------------- K1: per-step attention (one block per batch row) ----------------
__global__ __launch_bounds__(512) void k_attn2(
    const __bf16* __restrict__ u_hs,      // [25088][512] bf16
    const unsigned* __restrict__ enc2,    // enc bf16 pairs [25088][256]
    const unsigned* __restrict__ W2,      // [512][256] packed Ww^T
    const float* __restrict__ Wb, const float* __restrict__ Aw,
    __bf16* __restrict__ Abuf,            // [128][1024]: read h (512..1023), write ctx (0..511)
    float* __restrict__ alphas, int s) {
    __shared__ __align__(16) float hs[512];
    __shared__ float wah[512];
    __shared__ float pc[1024];
    __shared__ float sc[200];
    __shared__ float red[256];
    __shared__ float al[200];
    int b = blockIdx.x, t = threadIdx.x;
    int ln = t & 63, w = t >> 6;

    // h (bf16) -> LDS f32
    if (t < 256) {
        unsigned u = ((const unsigned*)Abuf)[b * 512 + 256 + t];
        hs[2 * t] = bflo(u); hs[2 * t + 1] = bfhi(u);
    }
    __syncthreads();
    // w_ah = h @ Ww^T + Wb  (coalesced packed W2, 2-way k-split)
    {
        int jp = t & 255, q = t >> 8;
        float a0 = 0.f, a1 = 0.f;
        const unsigned* wp = W2 + (size_t)(q * 256) * 256 + jp;
        const float4* h4 = (const float4*)(hs + q * 256);
#pragma unroll 4
        for (int k4 = 0; k4 < 64; ++k4) {
            float4 hk = h4[k4];
            unsigned w0 = wp[(k4 * 4 + 0) * 256];
            unsigned w1 = wp[(k4 * 4 + 1) * 256];
            unsigned w2 = wp[(k4 * 4 + 2) * 256];
            unsigned w3 = wp[(k4 * 4 + 3) * 256];
            a0 += hk.x * bflo(w0); a1 += hk.x * bfhi(w0);
            a0 += hk.y * bflo(w1); a1 += hk.y * bfhi(w1);
            a0 += hk.z * bflo(w2); a1 += hk.z * bfhi(w2);
            a0 += hk.w * bflo(w3); a1 += hk.w * bfhi(w3);
        }
        pc[q * 512 + 2 * jp] = a0;
        pc[q * 512 + 2 * jp + 1] = a1;
    }
    __syncthreads();
    wah[t] = pc[t] + pc[512 + t] + Wb[t];
    __syncthreads();
    // scores: 196 rows over 8 waves
    {
        float av[8], wv[8];
#pragma unroll
        for (int i = 0; i < 8; ++i) { av[i] = Aw[ln * 8 + i]; wv[i] = wah[ln * 8 + i]; }
        for (int n = w; n < NF_; n += 8) {
            bf16x8 u8 = *(const bf16x8*)(u_hs + ((size_t)(b * NF_ + n)) * 512 + ln * 8);
            float acc = 0.f;
#pragma unroll
            for (int i = 0; i < 8; ++i)
                acc += fast_tanhf((float)u8[i] + wv[i]) * av[i];
#pragma unroll
            for (int off = 32; off; off >>= 1) acc += __shfl_xor(acc, off);
            if (ln == 0) sc[n] = acc;    // Ab omitted (cancels in softmax)
        }
    }
    __syncthreads();
    // softmax over 196 (256-thread tree; threads 256..511 just hit the syncs)
    if (t < 256) red[t] = (t < NF_) ? sc[t] : -1e30f;
    __syncthreads();
#pragma unroll
    for (int off = 128; off; off >>= 1) {
        if (t < off) red[t] = fmaxf(red[t], red[t + off]);
        __syncthreads();
    }
    float mx = red[0];
    __syncthreads();
    float e = (t < NF_) ? __expf(sc[t] - mx) : 0.f;
    if (t < 256) red[t] = e;
    __syncthreads();
#pragma unroll
    for (int off = 128; off; off >>= 1) {
        if (t < off) red[t] += red[t + off];
        __syncthreads();
    }
    float inv = __fdividef(1.f, red[0]);
    __syncthreads();
    if (t < NF_) {
        float a = e * inv;
        al[t] = a;
        alphas[((size_t)b * S_ + s) * NF_ + t] = a;
    }
    __syncthreads();
    // context = alpha @ enc (2-way row split), write bf16 into Abuf ctx half
    {
        int p2 = t & 255, q2 = t >> 8;
        float c0 = 0.f, c1 = 0.f;
        for (int i = q2; i < NF_; i += 2) {
            unsigned u = enc2[((size_t)(b * NF_ + i)) * 256 + p2];
            float a = al[i];
            c0 += a * bflo(u); c1 += a * bfhi(u);
        }
        pc[q2 * 512 + 2 * p2] = c0;
        pc[q2 * 512 + 2 * p2 + 1] = c1;
    }
    __syncthreads();
    Abuf[(size_t)b * 1024 + t] = (__bf16)(pc[t] + pc[512 + t]);
}

// ---------------- K2: gates MFMA GEMM [128 x 2048 x 1024] + fused LSTM pointwise ----------------
// Wcat columns gate-interleaved so each lane's 4 N-fragments = the 4 gates of one unit.
__global__ __launch_bounds__(256) void k_gates(
    const __bf16* __restrict__ Abuf,      // [128][1024] = [ctx(s) | h(s)]
    const __bf16* __restrict__ Wcat,      // [2048][1024]
    const __bf16* __restrict__ gatespre,  // [3200][2048] bf16, gate-interleaved cols
    float* __restrict__ cbuf,             // [128][512] f32
    __bf16* __restrict__ AbufN,           // [128][1024]: write h(s+1) into cols 512..1023
    __bf16* __restrict__ Hall_bf,         // [26][128][512]
    int s) {
    __shared__ __align__(16) __bf16 As[128 * 64];
    __shared__ __align__(16) __bf16 Bs[128 * 64];
    int tid = threadIdx.x;
    int lane = tid & 63, w = tid >> 6;
    int n0 = blockIdx.x * 128;
    int wm = (w & 1) * 64, wn = (w >> 1) * 64;
    f32x4 acc[4][4] = {};
    int srow = tid >> 3;
    int ke = (tid & 7) * 8;
    int kgw = tid & 7;

    for (int k0 = 0; k0 < 1024; k0 += 64) {
#pragma unroll
        for (int it = 0; it < 4; ++it) {
            int row = it * 32 + srow;
            bf16x8 av = *(const bf16x8*)(Abuf + (size_t)row * 1024 + k0 + ke);
            bf16x8 bv = *(const bf16x8*)(Wcat + (size_t)(n0 + row) * 1024 + k0 + ke);
            int kg = kgw ^ (row & 7);
            *(bf16x8*)&As[row * 64 + kg * 8] = av;
            *(bf16x8*)&Bs[row * 64 + kg * 8] = bv;
        }
        __syncthreads();
        bf16x8 af[4][2], bfr[4][2];
#pragma unroll
        for (int f = 0; f < 4; ++f) {
#pragma unroll
            for (int ks = 0; ks < 2; ++ks) {
                int ra = wm + f * 16 + (lane & 15);
                int rb = wn + f * 16 + (lane & 15);
                int kgl = ks * 4 + (lane >> 4);
                af[f][ks]  = *(const bf16x8*)&As[ra * 64 + (kgl ^ (ra & 7)) * 8];
                bfr[f][ks] = *(const bf16x8*)&Bs[rb * 64 + (kgl ^ (rb & 7)) * 8];
            }
        }
#pragma unroll
        for (int fm = 0; fm < 4; ++fm)
#pragma unroll
            for (int fn = 0; fn < 4; ++fn)
#pragma unroll
                for (int ks = 0; ks < 2; ++ks)
                    acc[fm][fn] = __builtin_amdgcn_mfma_f32_16x16x32_bf16(
                        af[fm][ks], bfr[fn][ks], acc[fm][fn], 0, 0, 0);
        __syncthreads();
    }
    // epilogue: lane owns unit j for all 4 gates (fn = gate)
    int cm = (lane >> 4) * 4, cn = lane & 15;
    int j = ((n0 + wn) >> 6) * 16 + cn;
#pragma unroll
    for (int fm = 0; fm < 4; ++fm) {
#pragma unroll
        for (int r = 0; r < 4; ++r) {
            int b = wm + fm * 16 + cm + r;
            const __bf16* gp = gatespre + ((size_t)(s * B_ + b)) * G4_ + n0 + wn + cn;
            float qi = acc[fm][0][r] + (float)gp[0];
            float qf = acc[fm][1][r] + (float)gp[16];
            float qg = acc[fm][2][r] + (float)gp[32];
            float qo = acc[fm][3][r] + (float)gp[48];
            float ig = fast_sigf(qi), fg = fast_sigf(qf);
            float gg = fast_tanhf(qg), og = fast_sigf(qo);
            int ci = b * 512 + j;
            float cnew = fg * cbuf[ci] + ig * gg;
            float hn = og * fast_tanhf(cnew);
            cbuf[ci] = cnew;
            __bf16 hb = (__bf16)hn;
            AbufN[(size_t)b * 1024 + 512 + j] = hb;
            Hall_bf[(size_t)(s + 1) * 65536 + ci] = hb;
        }
    }
}

extern "C" void kernel_launch(void* const* d_in, const int* in_sizes, int n_in,
                              void* d_out, int out_size, void* d_ws, size_t ws_size,
                              hipStream_t stream) {
    const int*   dec  = (const int*)d_in[0];
    const float* enc  = (const float*)d_in[1];
    const float* emb  = (const float*)d_in[2];
    const float* pose = (const float*)d_in[3];
    const float* Uw   = (const float*)d_in[4];
    const float* Ub   = (const float*)d_in[5];
    const float* Ww   = (const float*)d_in[6];
    const float* Wb   = (const float*)d_in[7];
    const float* Aw   = (const float*)d_in[8];
    // d_in[9] = Ab: cancels in softmax
    const float* ihw  = (const float*)d_in[10];
    const float* ihb  = (const float*)d_in[11];
    const float* icw  = (const float*)d_in[12];
    const float* icb  = (const float*)d_in[13];
    const float* W_ih = (const float*)d_in[14];
    const float* W_hh = (const float*)d_in[15];
    const float* b_ih = (const float*)d_in[16];
    const float* b_hh = (const float*)d_in[17];
    const float* fcw  = (const float*)d_in[18];
    const float* fcb  = (const float*)d_in[19];
    float* out = (float*)d_out;
    char*  wsb = (char*)d_ws;

    // ---- workspace layout (bytes), ~87 MB ----
    size_t o = 0;
    __bf16*   enc_bf   = (__bf16*)(wsb + o); o += (size_t)25088 * 512 * 2;   // 25,690,112
    __bf16*   u_hs_bf  = (__bf16*)(wsb + o); o += (size_t)25088 * 512 * 2;   // 25,690,112
    __bf16*   gpre_bf  = (__bf16*)(wsb + o); o += (size_t)3200 * 2048 * 2;   // 13,107,200
    __bf16*   Hall_bf  = (__bf16*)(wsb + o); o += (size_t)26 * 65536 * 2;    //  3,407,872
    float*    cbuf     = (float*)(wsb + o);  o += (size_t)65536 * 4;         //    262,144
    __bf16*   Abuf     = (__bf16*)(wsb + o); o += (size_t)2 * 128 * 1024 * 2;//    524,288
    __bf16*   Uw_bf    = (__bf16*)(wsb + o); o += (size_t)262144 * 2;        //    524,288
    unsigned* W2       = (unsigned*)(wsb + o); o += (size_t)512 * 256 * 4;   //    524,288
    __bf16*   WihE_r   = (__bf16*)(wsb + o); o += (size_t)2048 * 256 * 2;    //  1,048,576
    __bf16*   embeds_bf= (__bf16*)(wsb + o); o += (size_t)3200 * 256 * 2;    //  1,638,400
    __bf16*   Wcat     = (__bf16*)(wsb + o); o += (size_t)2048 * 1024 * 2;   //  4,194,304
    float*    bsum_r   = (float*)(wsb + o);  o += (size_t)2048 * 4;          //      8,192
    __bf16*   fcw_bf   = (__bf16*)(wsb + o); o += (size_t)VPAD_ * 512 * 2;   // 10,354,688

    // ---- setup (independent) ----
    k_cvt<<<12544, 256, 0, stream>>>(enc, enc_bf, 3211264);
    k_cvt<<<256, 256, 0, stream>>>(Uw, Uw_bf, 65536);
    k_pack_ww<<<dim3(16, 8), 256, 0, stream>>>(Ww, W2);
    k_cvt_wih_r<<<2048, 256, 0, stream>>>(W_ih, WihE_r);
    k_pack_wcat<<<2048, 256, 0, stream>>>(W_ih, W_hh, Wcat);
    k_pack_biasr<<<8, 256, 0, stream>>>(b_ih, b_hh, bsum_r);
    k_embed<<<S_ * B_, 256, 0, stream>>>(dec, emb, pose, embeds_bf);
    k_init<<<B_, 256, 0, stream>>>(enc, ihw, ihb, icw, icb, Abuf, cbuf);
    k_cvt_fcw<<<5056, 256, 0, stream>>>(fcw, fcw_bf);

    // u_hs = enc @ Uw^T + Ub -> bf16 [25088,512]
    k_mfma_gemm<1><<<dim3(196, 4), 256, 0, stream>>>(enc_bf, 512, Uw_bf, Ub,
                                                     u_hs_bf, 512, 512, 512);
    // gates_pre = embeds @ WihE_r^T + bsum_r -> bf16 [3200,2048] (gate-interleaved cols)
    k_mfma_gemm<1><<<dim3(25, 16), 256, 0, stream>>>(embeds_bf, 256, WihE_r, bsum_r,
                                                     gpre_bf, 256, 2048, 2048);

    // ---- 25 steps x 2 kernels ----
    for (int s = 0; s < S_; ++s) {
        __bf16* Ap = Abuf + (size_t)(s & 1) * 131072;
        __bf16* An = Abuf + (size_t)((s + 1) & 1) * 131072;
        k_attn2<<<B_, 512, 0, stream>>>(u_hs_bf, (const unsigned*)enc_bf, W2, Wb, Aw,
                                        Ap, out + 32000000, s);
        k_gates<<<16, 256, 0, stream>>>(Ap, Wcat, gpre_bf, cbuf, An, Hall_bf, s);
    }

    // outs = Hall_bf[1..25] @ fcn_w^T + fcn_b -> f32 [B,S,V]
    k_mfma_gemm<0><<<dim3(25, 79), 256, 0, stream>>>(Hall_bf + 65536, 512, fcw_bf, fcb,
                                                     out, 512, V_, V_);
}

// Round 7
// 1904.891 us; speedup vs baseline: 2.6287x; 1.1781x over previous
//
#include <hip/hip_runtime.h>

constexpr int B_ = 128, S_ = 25, NF_ = 196, ENC_ = 512, ATT_ = 512;
constexpr int H_ = 512, E_ = 256, V_ = 10000, G4_ = 2048;
constexpr int VPAD_ = 10112;  // 79*128

typedef __attribute__((ext_vector_type(8))) __bf16 bf16x8;
typedef __attribute__((ext_vector_type(4))) __bf16 bf16x4;
typedef __attribute__((ext_vector_type(4))) float f32x4;

__device__ __forceinline__ float bflo(unsigned u) {
    return __builtin_bit_cast(float, u << 16);
}
__device__ __forceinline__ float bfhi(unsigned u) {
    return __builtin_bit_cast(float, u & 0xffff0000u);
}
__device__ __forceinline__ float fast_tanhf(float x) {
    x = fminf(fmaxf(x, -15.f), 15.f);
    return 1.f - 2.f * __fdividef(1.f, __expf(2.f * x) + 1.f);
}
__device__ __forceinline__ float fast_sigf(float x) {
    x = fminf(fmaxf(x, -30.f), 30.f);
    return __fdividef(1.f, 1.f + __expf(-x));
}

// gate-interleaved permutation: col n -> weight row pi(n)
__device__ __forceinline__ int gperm(int n) {
    int j = (n & 15) + ((n >> 6) << 4);
    int g = (n >> 4) & 3;
    return g * 512 + j;
}

// ---------------- setup kernels ----------------
__global__ __launch_bounds__(256) void k_cvt(const float* __restrict__ s,
                                             __bf16* __restrict__ d, int n4) {
    int i = blockIdx.x * 256 + threadIdx.x;
    if (i >= n4) return;
    float4 v = *(const float4*)&s[(size_t)i * 4];
    bf16x4 o;
    o[0] = (__bf16)v.x; o[1] = (__bf16)v.y; o[2] = (__bf16)v.z; o[3] = (__bf16)v.w;
    *(bf16x4*)&d[(size_t)i * 4] = o;
}

__global__ __launch_bounds__(256) void k_cvt_fcw(const float* __restrict__ s,
                                                 __bf16* __restrict__ d) {
    int i = blockIdx.x * 256 + threadIdx.x;
    if (i >= VPAD_ * 512 / 4) return;
    int e = i * 4;
    int row = e >> 9;
    bf16x4 o;
    if (row < V_) {
        float4 v = *(const float4*)&s[(size_t)row * 512 + (e & 511)];
        o[0] = (__bf16)v.x; o[1] = (__bf16)v.y; o[2] = (__bf16)v.z; o[3] = (__bf16)v.w;
    } else {
        o[0] = o[1] = o[2] = o[3] = (__bf16)0.f;
    }
    *(bf16x4*)&d[(size_t)e] = o;
}

// Ww[j][k] f32 -> W2[k][jp] u32 = pack(bf16 Ww[2jp][k], bf16 Ww[2jp+1][k])
__global__ __launch_bounds__(256) void k_pack_ww(const float* __restrict__ Ww,
                                                 unsigned* __restrict__ W2) {
    __shared__ float Ts[32][65];
    int t = threadIdx.x;
    int k0 = blockIdx.x * 32, j0 = blockIdx.y * 64;
    int c = t & 31, rr = t >> 5;
#pragma unroll
    for (int i = 0; i < 8; ++i) {
        int j = j0 + rr + i * 8;
        Ts[c][rr + i * 8] = Ww[(size_t)j * 512 + k0 + c];
    }
    __syncthreads();
#pragma unroll
    for (int i = 0; i < 4; ++i) {
        int kr = (t >> 5) + i * 8;
        int jc = t & 31;
        __bf16 b0 = (__bf16)Ts[kr][2 * jc], b1 = (__bf16)Ts[kr][2 * jc + 1];
        unsigned u = (unsigned)__builtin_bit_cast(unsigned short, b0)
                   | ((unsigned)__builtin_bit_cast(unsigned short, b1) << 16);
        W2[(size_t)(k0 + kr) * 256 + (j0 >> 1) + jc] = u;
    }
}

// W_ih[:, :256] permuted rows -> bf16 [2048][256] (gate-interleaved)
__global__ __launch_bounds__(256) void k_cvt_wih_r(const float* __restrict__ W_ih,
                                                   __bf16* __restrict__ o) {
    int n = blockIdx.x, k = threadIdx.x;
    int row = gperm(n);
    o[(size_t)n * 256 + k] = (__bf16)W_ih[(size_t)row * 768 + k];
}

// Wcat[n][k]: k<512 -> W_ih[pi(n)][256+k], else W_hh[pi(n)][k-512]   (bf16)
__global__ __launch_bounds__(256) void k_pack_wcat(const float* __restrict__ W_ih,
                                                   const float* __restrict__ W_hh,
                                                   __bf16* __restrict__ Wcat) {
    int n = blockIdx.x, t = threadIdx.x;
    int row = gperm(n);
#pragma unroll
    for (int i = 0; i < 4; ++i) {
        int k = t + i * 256;
        float v = (k < 512) ? W_ih[(size_t)row * 768 + 256 + k]
                            : W_hh[(size_t)row * 512 + (k - 512)];
        Wcat[(size_t)n * 1024 + k] = (__bf16)v;
    }
}

__global__ __launch_bounds__(256) void k_pack_biasr(const float* __restrict__ b_ih,
                                                    const float* __restrict__ b_hh,
                                                    float* __restrict__ bsum_r) {
    int n = blockIdx.x * 256 + threadIdx.x;
    int row = gperm(n);
    bsum_r[n] = b_ih[row] + b_hh[row];
}

__global__ __launch_bounds__(256) void k_embed(const int* __restrict__ dec,
                                               const float* __restrict__ emb,
                                               const float* __restrict__ pose,
                                               __bf16* __restrict__ out) {
    int bx = blockIdx.x;
    int s = bx >> 7, b = bx & 127;
    int e = threadIdx.x;
    int tok = dec[b * S_ + s];
    out[(size_t)bx * E_ + e] = (__bf16)(emb[tok * E_ + e] + pose[s * E_ + e]);
}

// mean_enc -> h0 (bf16 into Abuf0 h-part), c0 (f32 cbuf). Coalesced GEMV (wave-per-j).
__global__ __launch_bounds__(1024) void k_init2(const float* __restrict__ enc,
                                                const float* __restrict__ ihw, const float* __restrict__ ihb,
                                                const float* __restrict__ icw, const float* __restrict__ icb,
                                                __bf16* __restrict__ Abuf0, float* __restrict__ cbuf) {
    __shared__ float pm[1024];
    __shared__ __align__(16) float mean[512];
    int b = blockIdx.x, t = threadIdx.x;
    int d = t & 511, q = t >> 9;
    const float* ep = enc + ((size_t)b * 196 + q * 98) * 512 + d;
    float sum = 0.f;
#pragma unroll 7
    for (int n = 0; n < 98; ++n) sum += ep[(size_t)n * 512];
    pm[t] = sum;
    __syncthreads();
    if (t < 512) mean[t] = (pm[t] + pm[t + 512]) * (1.f / 196.f);
    __syncthreads();
    int w = t >> 6, ln = t & 63;
    float4 m4a = *(const float4*)&mean[ln * 8];
    float4 m4b = *(const float4*)&mean[ln * 8 + 4];
#pragma unroll 4
    for (int i = 0; i < 32; ++i) {
        int j = i * 16 + w;
        const float4* wh = (const float4*)&ihw[(size_t)j * 512 + ln * 8];
        const float4* wc = (const float4*)&icw[(size_t)j * 512 + ln * 8];
        float4 ha = wh[0], hb = wh[1], ca = wc[0], cb = wc[1];
        float ah = m4a.x * ha.x + m4a.y * ha.y + m4a.z * ha.z + m4a.w * ha.w
                 + m4b.x * hb.x + m4b.y * hb.y + m4b.z * hb.z + m4b.w * hb.w;
        float ac = m4a.x * ca.x + m4a.y * ca.y + m4a.z * ca.z + m4a.w * ca.w
                 + m4b.x * cb.x + m4b.y * cb.y + m4b.z * cb.z + m4b.w * cb.w;
#pragma unroll
        for (int off = 32; off; off >>= 1) {
            ah += __shfl_xor(ah, off);
            ac += __shfl_xor(ac, off);
        }
        if (ln == 0) {
            Abuf0[(size_t)b * 1024 + 512 + j] = (__bf16)(ah + ihb[j]);
            cbuf[b * 512 + j] = ac + icb[j];
        }
    }
}

// ---------------- bf16 MFMA GEMM (proven core, + lda param) ----------------
// MODE 0: f32 out, remap row (s*128+b -> b*25+s), guard n<Nreal, +bias (fcn)
// MODE 1: bf16 out, +bias (u_hs, gatespre)
template<int MODE>
__global__ __launch_bounds__(256) void k_mfma_gemm(
    const __bf16* __restrict__ A, int lda, const __bf16* __restrict__ Bm,
    const float* __restrict__ bias1, void* __restrict__ Cout,
    int K, int Nreal, int ldc) {
    __shared__ __align__(16) __bf16 As[128 * 64];
    __shared__ __align__(16) __bf16 Bs[128 * 64];
    int tid = threadIdx.x;
    int lane = tid & 63, w = tid >> 6;
    int m0 = blockIdx.x * 128, n0 = blockIdx.y * 128;
    int wm = (w & 1) * 64, wn = (w >> 1) * 64;
    f32x4 acc[4][4] = {};
    int srow = tid >> 3;
    int ke = (tid & 7) * 8;
    int kgw = tid & 7;

    for (int k0 = 0; k0 < K; k0 += 64) {
#pragma unroll
        for (int it = 0; it < 4; ++it) {
            int row = it * 32 + srow;
            bf16x8 av = *(const bf16x8*)(A + (size_t)(m0 + row) * lda + k0 + ke);
            bf16x8 bv = *(const bf16x8*)(Bm + (size_t)(n0 + row) * K + k0 + ke);
            int kg = kgw ^ (row & 7);
            *(bf16x8*)&As[row * 64 + kg * 8] = av;
            *(bf16x8*)&Bs[row * 64 + kg * 8] = bv;
        }
        __syncthreads();
        bf16x8 af[4][2], bfr[4][2];
#pragma unroll
        for (int f = 0; f < 4; ++f) {
#pragma unroll
            for (int ks = 0; ks < 2; ++ks) {
                int ra = wm + f * 16 + (lane & 15);
                int rb = wn + f * 16 + (lane & 15);
                int kgl = ks * 4 + (lane >> 4);
                af[f][ks]  = *(const bf16x8*)&As[ra * 64 + (kgl ^ (ra & 7)) * 8];
                bfr[f][ks] = *(const bf16x8*)&Bs[rb * 64 + (kgl ^ (rb & 7)) * 8];
            }
        }
#pragma unroll
        for (int fm = 0; fm < 4; ++fm)
#pragma unroll
            for (int fn = 0; fn < 4; ++fn)
#pragma unroll
                for (int ks = 0; ks < 2; ++ks)
                    acc[fm][fn] = __builtin_amdgcn_mfma_f32_16x16x32_bf16(
                        af[fm][ks], bfr[fn][ks], acc[fm][fn], 0, 0, 0);
        __syncthreads();
    }
    int cm = (lane >> 4) * 4, cn = lane & 15;
#pragma unroll
    for (int fm = 0; fm < 4; ++fm) {
#pragma unroll
        for (int fn = 0; fn < 4; ++fn) {
#pragma unroll
            for (int r = 0; r < 4; ++r) {
                int gm = m0 + wm + fm * 16 + cm + r;
                int gn = n0 + wn + fn * 16 + cn;
                float v = acc[fm][fn][r];
                if (MODE == 0) {
                    if (gn < Nreal) {
                        int orow = (gm & 127) * S_ + (gm >> 7);
                        ((float*)Cout)[(size_t)orow * ldc + gn] = v + bias1[gn];
                    }
                } else {
                    ((__bf16*)Cout)[(size_t)gm * ldc + gn] = (__bf16)(v + bias1[gn]);
                }
            }
        }
    }
}

// ---------------- K1: per-step attention (one block per batch row; R6-proven) ----------------
__global__ __launch_bounds__(512) void k_attn2(
    const __bf16* __restrict__ u_hs,      // [25088][512] bf16
    const unsigned* __restrict__ enc2,    // enc bf16 pairs [25088][256]
    const unsigned* __restrict__ W2,      // [512][256] packed Ww^T
    const float* __restrict__ Wb, const float* __restrict__ Aw,
    __bf16* __restrict__ Abuf,            // [128][1024]: read h (512..1023), write ctx (0..511)
    float* __restrict__ alphas, int s) {
    __shared__ __align__(16) float hs[512];
    __shared__ float wah[512];
    __shared__ float pc[1024];
    __shared__ float sc[200];
    __shared__ float red[256];
    __shared__ float al[200];
    int b = blockIdx.x, t = threadIdx.x;
    int ln = t & 63, w = t >> 6;

    // h (bf16) -> LDS f32
    if (t < 256) {
        unsigned u = ((const unsigned*)Abuf)[b * 512 + 256 + t];
        hs[2 * t] = bflo(u); hs[2 * t + 1] = bfhi(u);
    }
    __syncthreads();
    // w_ah = h @ Ww^T + Wb  (coalesced packed W2, 2-way k-split)
    {
        int jp = t & 255, q = t >> 8;
        float a0 = 0.f, a1 = 0.f;
        const unsigned* wp = W2 + (size_t)(q * 256) * 256 + jp;
        const float4* h4 = (const float4*)(hs + q * 256);
#pragma unroll 4
        for (int k4 = 0; k4 < 64; ++k4) {
            float4 hk = h4[k4];
            unsigned w0 = wp[(k4 * 4 + 0) * 256];
            unsigned w1 = wp[(k4 * 4 + 1) * 256];
            unsigned w2 = wp[(k4 * 4 + 2) * 256];
            unsigned w3 = wp[(k4 * 4 + 3) * 256];
            a0 += hk.x * bflo(w0); a1 += hk.x * bfhi(w0);
            a0 += hk.y * bflo(w1); a1 += hk.y * bfhi(w1);
            a0 += hk.z * bflo(w2); a1 += hk.z * bfhi(w2);
            a0 += hk.w * bflo(w3); a1 += hk.w * bfhi(w3);
        }
        pc[q * 512 + 2 * jp] = a0;
        pc[q * 512 + 2 * jp + 1] = a1;
    }
    __syncthreads();
    wah[t] = pc[t] + pc[512 + t] + Wb[t];
    __syncthreads();
    // scores: 196 rows over 8 waves
    {
        float av[8], wv[8];
#pragma unroll
        for (int i = 0; i < 8; ++i) { av[i] = Aw[ln * 8 + i]; wv[i] = wah[ln * 8 + i]; }
        for (int n = w; n < NF_; n += 8) {
            bf16x8 u8 = *(const bf16x8*)(u_hs + ((size_t)(b * NF_ + n)) * 512 + ln * 8);
            float acc = 0.f;
#pragma unroll
            for (int i = 0; i < 8; ++i)
                acc += fast_tanhf((float)u8[i] + wv[i]) * av[i];
#pragma unroll
            for (int off = 32; off; off >>= 1) acc += __shfl_xor(acc, off);
            if (ln == 0) sc[n] = acc;    // Ab omitted (cancels in softmax)
        }
    }
    __syncthreads();
    // softmax over 196 (256-thread tree; threads 256..511 just hit the syncs)
    if (t < 256) red[t] = (t < NF_) ? sc[t] : -1e30f;
    __syncthreads();
#pragma unroll
    for (int off = 128; off; off >>= 1) {
        if (t < off) red[t] = fmaxf(red[t], red[t + off]);
        __syncthreads();
    }
    float mx = red[0];
    __syncthreads();
    float e = (t < NF_) ? __expf(sc[t] - mx) : 0.f;
    if (t < 256) red[t] = e;
    __syncthreads();
#pragma unroll
    for (int off = 128; off; off >>= 1) {
        if (t < off) red[t] += red[t + off];
        __syncthreads();
    }
    float inv = __fdividef(1.f, red[0]);
    __syncthreads();
    if (t < NF_) {
        float a = e * inv;
        al[t] = a;
        alphas[((size_t)b * S_ + s) * NF_ + t] = a;
    }
    __syncthreads();
    // context = alpha @ enc (2-way row split), write bf16 into Abuf ctx half
    {
        int p2 = t & 255, q2 = t >> 8;
        float c0 = 0.f, c1 = 0.f;
        for (int i = q2; i < NF_; i += 2) {
            unsigned u = enc2[((size_t)(b * NF_ + i)) * 256 + p2];
            float a = al[i];
            c0 += a * bflo(u); c1 += a * bfhi(u);
        }
        pc[q2 * 512 + 2 * p2] = c0;
        pc[q2 * 512 + 2 * p2 + 1] = c1;
    }
    __syncthreads();
    Abuf[(size_t)b * 1024 + t] = (__bf16)(pc[t] + pc[512 + t]);
}

// ---------------- K2: gates MFMA GEMM 64x64 tiles (grid 2x32 = 64 blocks) ----------------
// Waves 4x1 over M (wm = w*16), fn = gate. Each lane owns all 4 gates of unit j.
__global__ __launch_bounds__(256) void k_gates(
    const __bf16* __restrict__ Abuf,      // [128][1024] = [ctx(s) | h(s)]
    const __bf16* __restrict__ Wcat,      // [2048][1024]
    const __bf16* __restrict__ gatespre,  // [3200][2048] bf16, gate-interleaved cols
    float* __restrict__ cbuf,             // [128][512] f32
    __bf16* __restrict__ AbufN,           // [128][1024]: write h(s+1) into cols 512..1023
    __bf16* __restrict__ Hall_bf,         // [26][128][512]
    int s) {
    __shared__ __align__(16) __bf16 As[64 * 64];
    __shared__ __align__(16) __bf16 Bs[64 * 64];
    int tid = threadIdx.x;
    int lane = tid & 63, w = tid >> 6;
    int m0 = blockIdx.x * 64, n0 = blockIdx.y * 64;
    int wm = w * 16;
    f32x4 acc[4] = {};
    int srow = tid >> 3;          // 0..31
    int ke = (tid & 7) * 8;
    int kgw = tid & 7;

    for (int k0 = 0; k0 < 1024; k0 += 64) {
#pragma unroll
        for (int it = 0; it < 2; ++it) {
            int row = it * 32 + srow;
            bf16x8 av = *(const bf16x8*)(Abuf + (size_t)(m0 + row) * 1024 + k0 + ke);
            bf16x8 bv = *(const bf16x8*)(Wcat + (size_t)(n0 + row) * 1024 + k0 + ke);
            int kg = kgw ^ (row & 7);
            *(bf16x8*)&As[row * 64 + kg * 8] = av;
            *(bf16x8*)&Bs[row * 64 + kg * 8] = bv;
        }
        __syncthreads();
        bf16x8 af[2], bfr[4][2];
#pragma unroll
        for (int ks = 0; ks < 2; ++ks) {
            int ra = wm + (lane & 15);
            int kgl = ks * 4 + (lane >> 4);
            af[ks] = *(const bf16x8*)&As[ra * 64 + (kgl ^ (ra & 7)) * 8];
#pragma unroll
            for (int fn = 0; fn < 4; ++fn) {
                int rb = fn * 16 + (lane & 15);
                bfr[fn][ks] = *(const bf16x8*)&Bs[rb * 64 + (kgl ^ (rb & 7)) * 8];
            }
        }
#pragma unroll
        for (int fn = 0; fn < 4; ++fn)
#pragma unroll
            for (int ks = 0; ks < 2; ++ks)
                acc[fn] = __builtin_amdgcn_mfma_f32_16x16x32_bf16(
                    af[ks], bfr[fn][ks], acc[fn], 0, 0, 0);
        __syncthreads();
    }
    // epilogue: lane owns unit j for all 4 gates (fn = gate)
    int cm = (lane >> 4) * 4, cn = lane & 15;
    int j = (n0 >> 6) * 16 + cn;
#pragma unroll
    for (int r = 0; r < 4; ++r) {
        int b = m0 + wm + cm + r;
        const __bf16* gp = gatespre + ((size_t)(s * B_ + b)) * G4_ + n0 + cn;
        float qi = acc[0][r] + (float)gp[0];
        float qf = acc[1][r] + (float)gp[16];
        float qg = acc[2][r] + (float)gp[32];
        float qo = acc[3][r] + (float)gp[48];
        float ig = fast_sigf(qi), fg = fast_sigf(qf);
        float gg = fast_tanhf(qg), og = fast_sigf(qo);
        int ci = b * 512 + j;
        float cnew = fg * cbuf[ci] + ig * gg;
        float hn = og * fast_tanhf(cnew);
        cbuf[ci] = cnew;
        __bf16 hb = (__bf16)hn;
        AbufN[(size_t)b * 1024 + 512 + j] = hb;
        Hall_bf[(size_t)(s + 1) * 65536 + ci] = hb;
    }
}

extern "C" void kernel_launch(void* const* d_in, const int* in_sizes, int n_in,
                              void* d_out, int out_size, void* d_ws, size_t ws_size,
                              hipStream_t stream) {
    const int*   dec  = (const int*)d_in[0];
    const float* enc  = (const float*)d_in[1];
    const float* emb  = (const float*)d_in[2];
    const float* pose = (const float*)d_in[3];
    const float* Uw   = (const float*)d_in[4];
    const float* Ub   = (const float*)d_in[5];
    const float* Ww   = (const float*)d_in[6];
    const float* Wb   = (const float*)d_in[7];
    const float* Aw   = (const float*)d_in[8];
    // d_in[9] = Ab: cancels in softmax
    const float* ihw  = (const float*)d_in[10];
    const float* ihb  = (const float*)d_in[11];
    const float* icw  = (const float*)d_in[12];
    const float* icb  = (const float*)d_in[13];
    const float* W_ih = (const float*)d_in[14];
    const float* W_hh = (const float*)d_in[15];
    const float* b_ih = (const float*)d_in[16];
    const float* b_hh = (const float*)d_in[17];
    const float* fcw  = (const float*)d_in[18];
    const float* fcb  = (const float*)d_in[19];
    float* out = (float*)d_out;
    char*  wsb = (char*)d_ws;

    // ---- workspace layout (bytes), ~87 MB ----
    size_t o = 0;
    __bf16*   enc_bf   = (__bf16*)(wsb + o); o += (size_t)25088 * 512 * 2;   // 25,690,112
    __bf16*   u_hs_bf  = (__bf16*)(wsb + o); o += (size_t)25088 * 512 * 2;   // 25,690,112
    __bf16*   gpre_bf  = (__bf16*)(wsb + o); o += (size_t)3200 * 2048 * 2;   // 13,107,200
    __bf16*   Hall_bf  = (__bf16*)(wsb + o); o += (size_t)26 * 65536 * 2;    //  3,407,872
    float*    cbuf     = (float*)(wsb + o);  o += (size_t)65536 * 4;         //    262,144
    __bf16*   Abuf     = (__bf16*)(wsb + o); o += (size_t)2 * 128 * 1024 * 2;//    524,288
    __bf16*   Uw_bf    = (__bf16*)(wsb + o); o += (size_t)262144 * 2;        //    524,288
    unsigned* W2       = (unsigned*)(wsb + o); o += (size_t)512 * 256 * 4;   //    524,288
    __bf16*   WihE_r   = (__bf16*)(wsb + o); o += (size_t)2048 * 256 * 2;    //  1,048,576
    __bf16*   embeds_bf= (__bf16*)(wsb + o); o += (size_t)3200 * 256 * 2;    //  1,638,400
    __bf16*   Wcat     = (__bf16*)(wsb + o); o += (size_t)2048 * 1024 * 2;   //  4,194,304
    float*    bsum_r   = (float*)(wsb + o);  o += (size_t)2048 * 4;          //      8,192
    __bf16*   fcw_bf   = (__bf16*)(wsb + o); o += (size_t)VPAD_ * 512 * 2;   // 10,354,688

    // ---- setup (independent) ----
    k_cvt<<<12544, 256, 0, stream>>>(enc, enc_bf, 3211264);
    k_cvt<<<256, 256, 0, stream>>>(Uw, Uw_bf, 65536);
    k_pack_ww<<<dim3(16, 8), 256, 0, stream>>>(Ww, W2);
    k_cvt_wih_r<<<2048, 256, 0, stream>>>(W_ih, WihE_r);
    k_pack_wcat<<<2048, 256, 0, stream>>>(W_ih, W_hh, Wcat);
    k_pack_biasr<<<8, 256, 0, stream>>>(b_ih, b_hh, bsum_r);
    k_embed<<<S_ * B_, 256, 0, stream>>>(dec, emb, pose, embeds_bf);
    k_init2<<<B_, 1024, 0, stream>>>(enc, ihw, ihb, icw, icb, Abuf, cbuf);
    k_cvt_fcw<<<5056, 256, 0, stream>>>(fcw, fcw_bf);

    // u_hs = enc @ Uw^T + Ub -> bf16 [25088,512]
    k_mfma_gemm<1><<<dim3(196, 4), 256, 0, stream>>>(enc_bf, 512, Uw_bf, Ub,
                                                     u_hs_bf, 512, 512, 512);
    // gates_pre = embeds @ WihE_r^T + bsum_r -> bf16 [3200,2048] (gate-interleaved cols)
    k_mfma_gemm<1><<<dim3(25, 16), 256, 0, stream>>>(embeds_bf, 256, WihE_r, bsum_r,
                                                     gpre_bf, 256, 2048, 2048);

    // ---- 25 steps x 2 kernels ----
    for (int s = 0; s < S_; ++s) {
        __bf16* Ap = Abuf + (size_t)(s & 1) * 131072;
        __bf16* An = Abuf + (size_t)((s + 1) & 1) * 131072;
        k_attn2<<<B_, 512, 0, stream>>>(u_hs_bf, (const unsigned*)enc_bf, W2, Wb, Aw,
                                        Ap, out + 32000000, s);
        k_gates<<<dim3(2, 32), 256, 0, stream>>>(Ap, Wcat, gpre_bf, cbuf, An, Hall_bf, s);
    }

    // outs = Hall_bf[1..25] @ fcn_w^T + fcn_b -> f32 [B,S,V]
    k_mfma_gemm<0><<<dim3(25, 79), 256, 0, stream>>>(Hall_bf + 65536, 512, fcw_bf, fcb,
                                                     out, 512, V_, V_);
}

// Round 8
// 1426.395 us; speedup vs baseline: 3.5105x; 1.3355x over previous
//
#include <hip/hip_runtime.h>

constexpr int B_ = 128, S_ = 25, NF_ = 196, ENC_ = 512, ATT_ = 512;
constexpr int H_ = 512, E_ = 256, V_ = 10000, G4_ = 2048;
constexpr int VPAD_ = 10112;  // 79*128

typedef __attribute__((ext_vector_type(8))) __bf16 bf16x8;
typedef __attribute__((ext_vector_type(4))) __bf16 bf16x4;
typedef __attribute__((ext_vector_type(4))) float f32x4;

__device__ __forceinline__ float bflo(unsigned u) {
    return __builtin_bit_cast(float, u << 16);
}
__device__ __forceinline__ float bfhi(unsigned u) {
    return __builtin_bit_cast(float, u & 0xffff0000u);
}
__device__ __forceinline__ float fast_tanhf(float x) {
    x = fminf(fmaxf(x, -15.f), 15.f);
    return 1.f - 2.f * __fdividef(1.f, __expf(2.f * x) + 1.f);
}
__device__ __forceinline__ float fast_sigf(float x) {
    x = fminf(fmaxf(x, -30.f), 30.f);
    return __fdividef(1.f, 1.f + __expf(-x));
}

// gate-interleaved permutation: col n -> weight row pi(n)
__device__ __forceinline__ int gperm(int n) {
    int j = (n & 15) + ((n >> 6) << 4);
    int g = (n >> 4) & 3;
    return g * 512 + j;
}

// ---------------- setup kernels ----------------
__global__ __launch_bounds__(256) void k_cvt(const float* __restrict__ s,
                                             __bf16* __restrict__ d, int n4) {
    int i = blockIdx.x * 256 + threadIdx.x;
    if (i >= n4) return;
    float4 v = *(const float4*)&s[(size_t)i * 4];
    bf16x4 o;
    o[0] = (__bf16)v.x; o[1] = (__bf16)v.y; o[2] = (__bf16)v.z; o[3] = (__bf16)v.w;
    *(bf16x4*)&d[(size_t)i * 4] = o;
}

__global__ __launch_bounds__(256) void k_cvt_fcw(const float* __restrict__ s,
                                                 __bf16* __restrict__ d) {
    int i = blockIdx.x * 256 + threadIdx.x;
    if (i >= VPAD_ * 512 / 4) return;
    int e = i * 4;
    int row = e >> 9;
    bf16x4 o;
    if (row < V_) {
        float4 v = *(const float4*)&s[(size_t)row * 512 + (e & 511)];
        o[0] = (__bf16)v.x; o[1] = (__bf16)v.y; o[2] = (__bf16)v.z; o[3] = (__bf16)v.w;
    } else {
        o[0] = o[1] = o[2] = o[3] = (__bf16)0.f;
    }
    *(bf16x4*)&d[(size_t)e] = o;
}

// Ww[j][k] f32 -> W2[k][jp] u32 = pack(bf16 Ww[2jp][k], bf16 Ww[2jp+1][k])
__global__ __launch_bounds__(256) void k_pack_ww(const float* __restrict__ Ww,
                                                 unsigned* __restrict__ W2) {
    __shared__ float Ts[32][65];
    int t = threadIdx.x;
    int k0 = blockIdx.x * 32, j0 = blockIdx.y * 64;
    int c = t & 31, rr = t >> 5;
#pragma unroll
    for (int i = 0; i < 8; ++i) {
        int j = j0 + rr + i * 8;
        Ts[c][rr + i * 8] = Ww[(size_t)j * 512 + k0 + c];
    }
    __syncthreads();
#pragma unroll
    for (int i = 0; i < 4; ++i) {
        int kr = (t >> 5) + i * 8;
        int jc = t & 31;
        __bf16 b0 = (__bf16)Ts[kr][2 * jc], b1 = (__bf16)Ts[kr][2 * jc + 1];
        unsigned u = (unsigned)__builtin_bit_cast(unsigned short, b0)
                   | ((unsigned)__builtin_bit_cast(unsigned short, b1) << 16);
        W2[(size_t)(k0 + kr) * 256 + (j0 >> 1) + jc] = u;
    }
}

// W_ih[:, :256] permuted rows -> bf16 [2048][256] (gate-interleaved)
__global__ __launch_bounds__(256) void k_cvt_wih_r(const float* __restrict__ W_ih,
                                                   __bf16* __restrict__ o) {
    int n = blockIdx.x, k = threadIdx.x;
    int row = gperm(n);
    o[(size_t)n * 256 + k] = (__bf16)W_ih[(size_t)row * 768 + k];
}

// Wcat[n][k]: k<512 -> W_ih[pi(n)][256+k], else W_hh[pi(n)][k-512]   (bf16)
__global__ __launch_bounds__(256) void k_pack_wcat(const float* __restrict__ W_ih,
                                                   const float* __restrict__ W_hh,
                                                   __bf16* __restrict__ Wcat) {
    int n = blockIdx.x, t = threadIdx.x;
    int row = gperm(n);
#pragma unroll
    for (int i = 0; i < 4; ++i) {
        int k = t + i * 256;
        float v = (k < 512) ? W_ih[(size_t)row * 768 + 256 + k]
                            : W_hh[(size_t)row * 512 + (k - 512)];
        Wcat[(size_t)n * 1024 + k] = (__bf16)v;
    }
}

__global__ __launch_bounds__(256) void k_pack_biasr(const float* __restrict__ b_ih,
                                                    const float* __restrict__ b_hh,
                                                    float* __restrict__ bsum_r) {
    int n = blockIdx.x * 256 + threadIdx.x;
    int row = gperm(n);
    bsum_r[n] = b_ih[row] + b_hh[row];
}

__global__ __launch_bounds__(256) void k_embed(const int* __restrict__ dec,
                                               const float* __restrict__ emb,
                                               const float* __restrict__ pose,
                                               __bf16* __restrict__ out) {
    int bx = blockIdx.x;
    int s = bx >> 7, b = bx & 127;
    int e = threadIdx.x;
    int tok = dec[b * S_ + s];
    out[(size_t)bx * E_ + e] = (__bf16)(emb[tok * E_ + e] + pose[s * E_ + e]);
}

// mean_enc -> h0 (bf16 into Abuf0 h-part), c0 (f32 cbuf). Coalesced GEMV (wave-per-j).
__global__ __launch_bounds__(1024) void k_init2(const float* __restrict__ enc,
                                                const float* __restrict__ ihw, const float* __restrict__ ihb,
                                                const float* __restrict__ icw, const float* __restrict__ icb,
                                                __bf16* __restrict__ Abuf0, float* __restrict__ cbuf) {
    __shared__ float pm[1024];
    __shared__ __align__(16) float mean[512];
    int b = blockIdx.x, t = threadIdx.x;
    int d = t & 511, q = t >> 9;
    const float* ep = enc + ((size_t)b * 196 + q * 98) * 512 + d;
    float sum = 0.f;
#pragma unroll 7
    for (int n = 0; n < 98; ++n) sum += ep[(size_t)n * 512];
    pm[t] = sum;
    __syncthreads();
    if (t < 512) mean[t] = (pm[t] + pm[t + 512]) * (1.f / 196.f);
    __syncthreads();
    int w = t >> 6, ln = t & 63;
    float4 m4a = *(const float4*)&mean[ln * 8];
    float4 m4b = *(const float4*)&mean[ln * 8 + 4];
#pragma unroll 4
    for (int i = 0; i < 32; ++i) {
        int j = i * 16 + w;
        const float4* wh = (const float4*)&ihw[(size_t)j * 512 + ln * 8];
        const float4* wc = (const float4*)&icw[(size_t)j * 512 + ln * 8];
        float4 ha = wh[0], hb = wh[1], ca = wc[0], cb = wc[1];
        float ah = m4a.x * ha.x + m4a.y * ha.y + m4a.z * ha.z + m4a.w * ha.w
                 + m4b.x * hb.x + m4b.y * hb.y + m4b.z * hb.z + m4b.w * hb.w;
        float ac = m4a.x * ca.x + m4a.y * ca.y + m4a.z * ca.z + m4a.w * ca.w
                 + m4b.x * cb.x + m4b.y * cb.y + m4b.z * cb.z + m4b.w * cb.w;
#pragma unroll
        for (int off = 32; off; off >>= 1) {
            ah += __shfl_xor(ah, off);
            ac += __shfl_xor(ac, off);
        }
        if (ln == 0) {
            Abuf0[(size_t)b * 1024 + 512 + j] = (__bf16)(ah + ihb[j]);
            cbuf[b * 512 + j] = ac + icb[j];
        }
    }
}

// ---------------- bf16 MFMA GEMM (proven core, + lda param) ----------------
// MODE 0: f32 out, remap row (s*128+b -> b*25+s), guard n<Nreal, +bias (fcn)
// MODE 1: bf16 out, +bias (u_hs, gatespre)
template<int MODE>
__global__ __launch_bounds__(256) void k_mfma_gemm(
    const __bf16* __restrict__ A, int lda, const __bf16* __restrict__ Bm,
    const float* __restrict__ bias1, void* __restrict__ Cout,
    int K, int Nreal, int ldc) {
    __shared__ __align__(16) __bf16 As[128 * 64];
    __shared__ __align__(16) __bf16 Bs[128 * 64];
    int tid = threadIdx.x;
    int lane = tid & 63, w = tid >> 6;
    int m0 = blockIdx.x * 128, n0 = blockIdx.y * 128;
    int wm = (w & 1) * 64, wn = (w >> 1) * 64;
    f32x4 acc[4][4] = {};
    int srow = tid >> 3;
    int ke = (tid & 7) * 8;
    int kgw = tid & 7;

    for (int k0 = 0; k0 < K; k0 += 64) {
#pragma unroll
        for (int it = 0; it < 4; ++it) {
            int row = it * 32 + srow;
            bf16x8 av = *(const bf16x8*)(A + (size_t)(m0 + row) * lda + k0 + ke);
            bf16x8 bv = *(const bf16x8*)(Bm + (size_t)(n0 + row) * K + k0 + ke);
            int kg = kgw ^ (row & 7);
            *(bf16x8*)&As[row * 64 + kg * 8] = av;
            *(bf16x8*)&Bs[row * 64 + kg * 8] = bv;
        }
        __syncthreads();
        bf16x8 af[4][2], bfr[4][2];
#pragma unroll
        for (int f = 0; f < 4; ++f) {
#pragma unroll
            for (int ks = 0; ks < 2; ++ks) {
                int ra = wm + f * 16 + (lane & 15);
                int rb = wn + f * 16 + (lane & 15);
                int kgl = ks * 4 + (lane >> 4);
                af[f][ks]  = *(const bf16x8*)&As[ra * 64 + (kgl ^ (ra & 7)) * 8];
                bfr[f][ks] = *(const bf16x8*)&Bs[rb * 64 + (kgl ^ (rb & 7)) * 8];
            }
        }
#pragma unroll
        for (int fm = 0; fm < 4; ++fm)
#pragma unroll
            for (int fn = 0; fn < 4; ++fn)
#pragma unroll
                for (int ks = 0; ks < 2; ++ks)
                    acc[fm][fn] = __builtin_amdgcn_mfma_f32_16x16x32_bf16(
                        af[fm][ks], bfr[fn][ks], acc[fm][fn], 0, 0, 0);
        __syncthreads();
    }
    int cm = (lane >> 4) * 4, cn = lane & 15;
#pragma unroll
    for (int fm = 0; fm < 4; ++fm) {
#pragma unroll
        for (int fn = 0; fn < 4; ++fn) {
#pragma unroll
            for (int r = 0; r < 4; ++r) {
                int gm = m0 + wm + fm * 16 + cm + r;
                int gn = n0 + wn + fn * 16 + cn;
                float v = acc[fm][fn][r];
                if (MODE == 0) {
                    if (gn < Nreal) {
                        int orow = (gm & 127) * S_ + (gm >> 7);
                        ((float*)Cout)[(size_t)orow * ldc + gn] = v + bias1[gn];
                    }
                } else {
                    ((__bf16*)Cout)[(size_t)gm * ldc + gn] = (__bf16)(v + bias1[gn]);
                }
            }
        }
    }
}

// ---------------- K1: per-step attention, 1024 threads (R5/R6-proven sub-patterns) ----------------
__global__ __launch_bounds__(1024) void k_attn2(
    const __bf16* __restrict__ u_hs,      // [25088][512] bf16
    const unsigned* __restrict__ enc2,    // enc bf16 pairs [25088][256]
    const unsigned* __restrict__ W2,      // [512][256] packed Ww^T
    const float* __restrict__ Wb, const float* __restrict__ Aw,
    __bf16* __restrict__ Abuf,            // [128][1024]: read h (512..1023), write ctx (0..511)
    float* __restrict__ alphas, int s) {
    __shared__ __align__(16) float hs[512];
    __shared__ float wah[512];
    __shared__ float pc[2048];
    __shared__ float sc[200];
    __shared__ float red[256];
    __shared__ float al[200];
    int b = blockIdx.x, t = threadIdx.x;
    int ln = t & 63, w = t >> 6;

    // h (bf16) -> LDS f32
    if (t < 256) {
        unsigned u = ((const unsigned*)Abuf)[b * 512 + 256 + t];
        hs[2 * t] = bflo(u); hs[2 * t + 1] = bfhi(u);
    }
    __syncthreads();
    // w_ah = h @ Ww^T + Wb  (coalesced packed W2, 4-way k-split — R5-proven)
    {
        int jp = t & 255, kq = t >> 8;
        float a0 = 0.f, a1 = 0.f;
        const unsigned* wp = W2 + (size_t)(kq * 128) * 256 + jp;
        const float4* h4 = (const float4*)(hs + kq * 128);
#pragma unroll 4
        for (int k4 = 0; k4 < 32; ++k4) {
            float4 hk = h4[k4];
            unsigned w0 = wp[(k4 * 4 + 0) * 256];
            unsigned w1 = wp[(k4 * 4 + 1) * 256];
            unsigned w2 = wp[(k4 * 4 + 2) * 256];
            unsigned w3 = wp[(k4 * 4 + 3) * 256];
            a0 += hk.x * bflo(w0); a1 += hk.x * bfhi(w0);
            a0 += hk.y * bflo(w1); a1 += hk.y * bfhi(w1);
            a0 += hk.z * bflo(w2); a1 += hk.z * bfhi(w2);
            a0 += hk.w * bflo(w3); a1 += hk.w * bfhi(w3);
        }
        pc[kq * 512 + 2 * jp] = a0;
        pc[kq * 512 + 2 * jp + 1] = a1;
    }
    __syncthreads();
    if (t < 512)
        wah[t] = pc[t] + pc[512 + t] + pc[1024 + t] + pc[1536 + t] + Wb[t];
    __syncthreads();
    // scores: 196 rows over 16 waves
    {
        float av[8], wv[8];
#pragma unroll
        for (int i = 0; i < 8; ++i) { av[i] = Aw[ln * 8 + i]; wv[i] = wah[ln * 8 + i]; }
        for (int n = w; n < NF_; n += 16) {
            bf16x8 u8 = *(const bf16x8*)(u_hs + ((size_t)(b * NF_ + n)) * 512 + ln * 8);
            float acc = 0.f;
#pragma unroll
            for (int i = 0; i < 8; ++i)
                acc += fast_tanhf((float)u8[i] + wv[i]) * av[i];
#pragma unroll
            for (int off = 32; off; off >>= 1) acc += __shfl_xor(acc, off);
            if (ln == 0) sc[n] = acc;    // Ab omitted (cancels in softmax)
        }
    }
    __syncthreads();
    // softmax over 196 (256-thread tree; other threads hit the syncs)
    if (t < 256) red[t] = (t < NF_) ? sc[t] : -1e30f;
    __syncthreads();
#pragma unroll
    for (int off = 128; off; off >>= 1) {
        if (t < off) red[t] = fmaxf(red[t], red[t + off]);
        __syncthreads();
    }
    float mx = red[0];
    __syncthreads();
    float e = (t < NF_) ? __expf(sc[t] - mx) : 0.f;
    if (t < 256) red[t] = e;
    __syncthreads();
#pragma unroll
    for (int off = 128; off; off >>= 1) {
        if (t < off) red[t] += red[t + off];
        __syncthreads();
    }
    float inv = __fdividef(1.f, red[0]);
    __syncthreads();
    if (t < NF_) {
        float a = e * inv;
        al[t] = a;
        alphas[((size_t)b * S_ + s) * NF_ + t] = a;
    }
    __syncthreads();
    // context = alpha @ enc (4-way row split), write bf16 into Abuf ctx half
    {
        int p2 = t & 255, q2 = t >> 8;
        float c0 = 0.f, c1 = 0.f;
        for (int i = q2; i < NF_; i += 4) {
            unsigned u = enc2[((size_t)(b * NF_ + i)) * 256 + p2];
            float a = al[i];
            c0 += a * bflo(u); c1 += a * bfhi(u);
        }
        pc[q2 * 512 + 2 * p2] = c0;
        pc[q2 * 512 + 2 * p2 + 1] = c1;
    }
    __syncthreads();
    if (t < 512)
        Abuf[(size_t)b * 1024 + t] =
            (__bf16)(pc[t] + pc[512 + t] + pc[1024 + t] + pc[1536 + t]);
}

// ---------------- K2: gates MFMA GEMM, 32x64 tiles + 2-way K-split (grid 4x32 = 128 blocks) ----------------
// Waves: kh = w>>1 owns K half, wm = (w&1)*16 owns 16 rows. fn = gate; lane owns unit j.
__global__ __launch_bounds__(256) void k_gates(
    const __bf16* __restrict__ Abuf,      // [128][1024] = [ctx(s) | h(s)]
    const __bf16* __restrict__ Wcat,      // [2048][1024]
    const __bf16* __restrict__ gatespre,  // [3200][2048] bf16, gate-interleaved cols
    float* __restrict__ cbuf,             // [128][512] f32
    __bf16* __restrict__ AbufN,           // [128][1024]: write h(s+1) into cols 512..1023
    __bf16* __restrict__ Hall_bf,         // [26][128][512]
    int s) {
    __shared__ __align__(16) __bf16 As[2][32 * 64];
    __shared__ __align__(16) __bf16 Bs[2][64 * 64];
    __shared__ float Red[2048];
    int tid = threadIdx.x;
    int lane = tid & 63, w = tid >> 6;
    int m0 = blockIdx.x * 32, n0 = blockIdx.y * 64;
    int kh = w >> 1, wm = (w & 1) * 16;
    f32x4 acc[4] = {};
    int srow = tid >> 3;          // 0..31
    int ke = (tid & 7) * 8;
    int kgw = tid & 7;

    for (int k0 = 0; k0 < 512; k0 += 64) {
#pragma unroll
        for (int h = 0; h < 2; ++h) {
            int kb = h * 512 + k0;
            bf16x8 av = *(const bf16x8*)(Abuf + (size_t)(m0 + srow) * 1024 + kb + ke);
            int kg = kgw ^ (srow & 7);
            *(bf16x8*)&As[h][srow * 64 + kg * 8] = av;
#pragma unroll
            for (int it = 0; it < 2; ++it) {
                int row = it * 32 + srow;
                bf16x8 bv = *(const bf16x8*)(Wcat + (size_t)(n0 + row) * 1024 + kb + ke);
                int kg2 = kgw ^ (row & 7);
                *(bf16x8*)&Bs[h][row * 64 + kg2 * 8] = bv;
            }
        }
        __syncthreads();
        bf16x8 af[2], bfr[4][2];
#pragma unroll
        for (int ks = 0; ks < 2; ++ks) {
            int ra = wm + (lane & 15);
            int kgl = ks * 4 + (lane >> 4);
            af[ks] = *(const bf16x8*)&As[kh][ra * 64 + ((kgl ^ (ra & 7))) * 8];
#pragma unroll
            for (int fn = 0; fn < 4; ++fn) {
                int rb = fn * 16 + (lane & 15);
                bfr[fn][ks] = *(const bf16x8*)&Bs[kh][rb * 64 + ((kgl ^ (rb & 7))) * 8];
            }
        }
#pragma unroll
        for (int fn = 0; fn < 4; ++fn)
#pragma unroll
            for (int ks = 0; ks < 2; ++ks)
                acc[fn] = __builtin_amdgcn_mfma_f32_16x16x32_bf16(
                    af[ks], bfr[fn][ks], acc[fn], 0, 0, 0);
        __syncthreads();
    }
    // reduce the kh=1 half into kh=0 waves
    int base = ((w & 1) * 64 + lane) * 16;
    if (kh == 1) {
#pragma unroll
        for (int fn = 0; fn < 4; ++fn)
#pragma unroll
            for (int r = 0; r < 4; ++r) Red[base + fn * 4 + r] = acc[fn][r];
    }
    __syncthreads();
    if (kh == 0) {
#pragma unroll
        for (int fn = 0; fn < 4; ++fn)
#pragma unroll
            for (int r = 0; r < 4; ++r) acc[fn][r] += Red[base + fn * 4 + r];
        // epilogue: lane owns unit j for all 4 gates (fn = gate)
        int cm = (lane >> 4) * 4, cn = lane & 15;
        int j = (n0 >> 6) * 16 + cn;
#pragma unroll
        for (int r = 0; r < 4; ++r) {
            int b = m0 + wm + cm + r;
            const __bf16* gp = gatespre + ((size_t)(s * B_ + b)) * G4_ + n0 + cn;
            float qi = acc[0][r] + (float)gp[0];
            float qf = acc[1][r] + (float)gp[16];
            float qg = acc[2][r] + (float)gp[32];
            float qo = acc[3][r] + (float)gp[48];
            float ig = fast_sigf(qi), fg = fast_sigf(qf);
            float gg = fast_tanhf(qg), og = fast_sigf(qo);
            int ci = b * 512 + j;
            float cnew = fg * cbuf[ci] + ig * gg;
            float hn = og * fast_tanhf(cnew);
            cbuf[ci] = cnew;
            __bf16 hb = (__bf16)hn;
            AbufN[(size_t)b * 1024 + 512 + j] = hb;
            Hall_bf[(size_t)(s + 1) * 65536 + ci] = hb;
        }
    }
}

extern "C" void kernel_launch(void* const* d_in, const int* in_sizes, int n_in,
                              void* d_out, int out_size, void* d_ws, size_t ws_size,
                              hipStream_t stream) {
    const int*   dec  = (const int*)d_in[0];
    const float* enc  = (const float*)d_in[1];
    const float* emb  = (const float*)d_in[2];
    const float* pose = (const float*)d_in[3];
    const float* Uw   = (const float*)d_in[4];
    const float* Ub   = (const float*)d_in[5];
    const float* Ww   = (const float*)d_in[6];
    const float* Wb   = (const float*)d_in[7];
    const float* Aw   = (const float*)d_in[8];
    // d_in[9] = Ab: cancels in softmax
    const float* ihw  = (const float*)d_in[10];
    const float* ihb  = (const float*)d_in[11];
    const float* icw  = (const float*)d_in[12];
    const float* icb  = (const float*)d_in[13];
    const float* W_ih = (const float*)d_in[14];
    const float* W_hh = (const float*)d_in[15];
    const float* b_ih = (const float*)d_in[16];
    const float* b_hh = (const float*)d_in[17];
    const float* fcw  = (const float*)d_in[18];
    const float* fcb  = (const float*)d_in[19];
    float* out = (float*)d_out;
    char*  wsb = (char*)d_ws;

    // ---- workspace layout (bytes), ~87 MB ----
    size_t o = 0;
    __bf16*   enc_bf   = (__bf16*)(wsb + o); o += (size_t)25088 * 512 * 2;   // 25,690,112
    __bf16*   u_hs_bf  = (__bf16*)(wsb + o); o += (size_t)25088 * 512 * 2;   // 25,690,112
    __bf16*   gpre_bf  = (__bf16*)(wsb + o); o += (size_t)3200 * 2048 * 2;   // 13,107,200
    __bf16*   Hall_bf  = (__bf16*)(wsb + o); o += (size_t)26 * 65536 * 2;    //  3,407,872
    float*    cbuf     = (float*)(wsb + o);  o += (size_t)65536 * 4;         //    262,144
    __bf16*   Abuf     = (__bf16*)(wsb + o); o += (size_t)2 * 128 * 1024 * 2;//    524,288
    __bf16*   Uw_bf    = (__bf16*)(wsb + o); o += (size_t)262144 * 2;        //    524,288
    unsigned* W2       = (unsigned*)(wsb + o); o += (size_t)512 * 256 * 4;   //    524,288
    __bf16*   WihE_r   = (__bf16*)(wsb + o); o += (size_t)2048 * 256 * 2;    //  1,048,576
    __bf16*   embeds_bf= (__bf16*)(wsb + o); o += (size_t)3200 * 256 * 2;    //  1,638,400
    __bf16*   Wcat     = (__bf16*)(wsb + o); o += (size_t)2048 * 1024 * 2;   //  4,194,304
    float*    bsum_r   = (float*)(wsb + o);  o += (size_t)2048 * 4;          //      8,192
    __bf16*   fcw_bf   = (__bf16*)(wsb + o); o += (size_t)VPAD_ * 512 * 2;   // 10,354,688

    // ---- setup (independent) ----
    k_cvt<<<12544, 256, 0, stream>>>(enc, enc_bf, 3211264);
    k_cvt<<<256, 256, 0, stream>>>(Uw, Uw_bf, 65536);
    k_pack_ww<<<dim3(16, 8), 256, 0, stream>>>(Ww, W2);
    k_cvt_wih_r<<<2048, 256, 0, stream>>>(W_ih, WihE_r);
    k_pack_wcat<<<2048, 256, 0, stream>>>(W_ih, W_hh, Wcat);
    k_pack_biasr<<<8, 256, 0, stream>>>(b_ih, b_hh, bsum_r);
    k_embed<<<S_ * B_, 256, 0, stream>>>(dec, emb, pose, embeds_bf);
    k_init2<<<B_, 1024, 0, stream>>>(enc, ihw, ihb, icw, icb, Abuf, cbuf);
    k_cvt_fcw<<<5056, 256, 0, stream>>>(fcw, fcw_bf);

    // u_hs = enc @ Uw^T + Ub -> bf16 [25088,512]
    k_mfma_gemm<1><<<dim3(196, 4), 256, 0, stream>>>(enc_bf, 512, Uw_bf, Ub,
                                                     u_hs_bf, 512, 512, 512);
    // gates_pre = embeds @ WihE_r^T + bsum_r -> bf16 [3200,2048] (gate-interleaved cols)
    k_mfma_gemm<1><<<dim3(25, 16), 256, 0, stream>>>(embeds_bf, 256, WihE_r, bsum_r,
                                                     gpre_bf, 256, 2048, 2048);

    // ---- 25 steps x 2 kernels ----
    for (int s = 0; s < S_; ++s) {
        __bf16* Ap = Abuf + (size_t)(s & 1) * 131072;
        __bf16* An = Abuf + (size_t)((s + 1) & 1) * 131072;
        k_attn2<<<B_, 1024, 0, stream>>>(u_hs_bf, (const unsigned*)enc_bf, W2, Wb, Aw,
                                         Ap, out + 32000000, s);
        k_gates<<<dim3(4, 32), 256, 0, stream>>>(Ap, Wcat, gpre_bf, cbuf, An, Hall_bf, s);
    }

    // outs = Hall_bf[1..25] @ fcn_w^T + fcn_b -> f32 [B,S,V]
    k_mfma_gemm<0><<<dim3(25, 79), 256, 0, stream>>>(Hall_bf + 65536, 512, fcw_bf, fcb,
                                                     out, 512, V_, V_);
}